// Round 2
// baseline (671.818 us; speedup 1.0000x reference)
//
#include <hip/hip_runtime.h>

#define NN 100000
#define NE 1600000
// IN_DIM=128, HID_DIM=64, OUT_DIM=16

// ---------------------------------------------------------------------------
// K1: y[n][o] = dot(x[n,:128], W[o,:128])   (W = W1_l, [64,128] row-major)
// 64-node tile per block, W staged in two 32-row halves (LDS budget 64KB).
// Thread map: og = tid&15 (o = hh*32 + og + 16i, i<2), ng = tid>>4 (n = n0+ng+16j, j<4)
// ---------------------------------------------------------------------------
__global__ __launch_bounds__(256) void k_gemm1(const float* __restrict__ x,
                                               const float* __restrict__ W,
                                               float* __restrict__ y) {
  __shared__ float xs[64 * 132];
  __shared__ float ws[32 * 132];
  const int tid = threadIdx.x;
  const int n0 = blockIdx.x * 64;

  for (int i = tid; i < 64 * 32; i += 256) {
    int r = i >> 5, c = i & 31;
    int n = n0 + r;
    float4 v = (n < NN) ? *(const float4*)&x[(size_t)n * 128 + c * 4]
                        : make_float4(0.f, 0.f, 0.f, 0.f);
    *(float4*)&xs[r * 132 + c * 4] = v;
  }

  const int og = tid & 15, ng = tid >> 4;

  for (int hh = 0; hh < 2; ++hh) {
    __syncthreads();  // xs ready (hh=0) / previous half's compute done (hh=1)
    for (int i = tid; i < 32 * 32; i += 256) {
      int r = i >> 5, c = i & 31;
      *(float4*)&ws[r * 132 + c * 4] = *(const float4*)&W[(hh * 32 + r) * 128 + c * 4];
    }
    __syncthreads();

    float acc[2][4] = {};
#pragma unroll 2
    for (int k4 = 0; k4 < 32; ++k4) {
      float4 wv[2], xv[4];
#pragma unroll
      for (int i = 0; i < 2; ++i) wv[i] = *(float4*)&ws[(og + 16 * i) * 132 + k4 * 4];
#pragma unroll
      for (int j = 0; j < 4; ++j) xv[j] = *(float4*)&xs[(ng + 16 * j) * 132 + k4 * 4];
#pragma unroll
      for (int i = 0; i < 2; ++i)
#pragma unroll
        for (int j = 0; j < 4; ++j)
          acc[i][j] += wv[i].x * xv[j].x + wv[i].y * xv[j].y +
                       wv[i].z * xv[j].z + wv[i].w * xv[j].w;
    }

#pragma unroll
    for (int j = 0; j < 4; ++j) {
      int n = n0 + ng + 16 * j;
      if (n < NN) {
#pragma unroll
        for (int i = 0; i < 2; ++i)
          y[(size_t)n * 64 + hh * 32 + og + 16 * i] = acc[i][j];
      }
    }
  }
}

// ---------------------------------------------------------------------------
// K2: per-edge scatter of y_l (64 feats). One wave per edge; lane d handles feat d.
// ---------------------------------------------------------------------------
__global__ __launch_bounds__(256) void k_scatter1(const int* __restrict__ ei,
                                                  const float* __restrict__ y,
                                                  float* __restrict__ sums,
                                                  float* __restrict__ cnt) {
  long long gid = (long long)blockIdx.x * 256 + threadIdx.x;
  int e = (int)(gid >> 6);
  if (e >= NE) return;
  int d = threadIdx.x & 63;
  int s = ei[e];
  int t = ei[NE + e];
  atomicAdd(&sums[(size_t)t * 64 + d], y[(size_t)s * 64 + d]);
  if (d == 0) atomicAdd(&cnt[t], 1.0f);
}

// ---------------------------------------------------------------------------
// K3: h = sums1/max(cnt,1) + b1 + x @ W1_r^T  (in-place over sums1)
//     + BatchNorm partial sums (sum, sumsq per feature) -> global bnacc[128]
// ---------------------------------------------------------------------------
__global__ __launch_bounds__(256) void k_l1finish(const float* __restrict__ x,
                                                  const float* __restrict__ W,
                                                  const float* __restrict__ b1,
                                                  const float* __restrict__ cnt,
                                                  float* __restrict__ hbuf,
                                                  float* __restrict__ bnacc) {
  __shared__ float xs[64 * 132];
  __shared__ float ws[32 * 132];
  __shared__ float bnS[64], bnQ[64];
  const int tid = threadIdx.x;
  const int n0 = blockIdx.x * 64;

  if (tid < 64) { bnS[tid] = 0.f; bnQ[tid] = 0.f; }

  for (int i = tid; i < 64 * 32; i += 256) {
    int r = i >> 5, c = i & 31;
    int n = n0 + r;
    float4 v = (n < NN) ? *(const float4*)&x[(size_t)n * 128 + c * 4]
                        : make_float4(0.f, 0.f, 0.f, 0.f);
    *(float4*)&xs[r * 132 + c * 4] = v;
  }

  const int og = tid & 15, ng = tid >> 4;
  int nn[4];
  float invc[4];
#pragma unroll
  for (int j = 0; j < 4; ++j) {
    nn[j] = n0 + ng + 16 * j;
    invc[j] = (nn[j] < NN) ? 1.0f / fmaxf(cnt[nn[j]], 1.0f) : 0.f;
  }

  for (int hh = 0; hh < 2; ++hh) {
    __syncthreads();
    for (int i = tid; i < 32 * 32; i += 256) {
      int r = i >> 5, c = i & 31;
      *(float4*)&ws[r * 132 + c * 4] = *(const float4*)&W[(hh * 32 + r) * 128 + c * 4];
    }
    __syncthreads();

    float acc[2][4] = {};
#pragma unroll 2
    for (int k4 = 0; k4 < 32; ++k4) {
      float4 wv[2], xv[4];
#pragma unroll
      for (int i = 0; i < 2; ++i) wv[i] = *(float4*)&ws[(og + 16 * i) * 132 + k4 * 4];
#pragma unroll
      for (int j = 0; j < 4; ++j) xv[j] = *(float4*)&xs[(ng + 16 * j) * 132 + k4 * 4];
#pragma unroll
      for (int i = 0; i < 2; ++i)
#pragma unroll
        for (int j = 0; j < 4; ++j)
          acc[i][j] += wv[i].x * xv[j].x + wv[i].y * xv[j].y +
                       wv[i].z * xv[j].z + wv[i].w * xv[j].w;
    }

    float sj[2] = {0.f, 0.f}, qj[2] = {0.f, 0.f};
#pragma unroll
    for (int j = 0; j < 4; ++j) {
      if (nn[j] < NN) {
#pragma unroll
        for (int i = 0; i < 2; ++i) {
          int o = hh * 32 + og + 16 * i;
          size_t idx = (size_t)nn[j] * 64 + o;
          float v = hbuf[idx] * invc[j] + b1[o] + acc[i][j];
          hbuf[idx] = v;
          sj[i] += v;
          qj[i] += v * v;
        }
      }
    }
    // reduce across the 4 lanes in this wave that share og (lane ^ 16, ^ 32)
#pragma unroll
    for (int i = 0; i < 2; ++i) {
      sj[i] += __shfl_xor(sj[i], 16);
      sj[i] += __shfl_xor(sj[i], 32);
      qj[i] += __shfl_xor(qj[i], 16);
      qj[i] += __shfl_xor(qj[i], 32);
    }
    if (((tid >> 4) & 3) == 0) {
#pragma unroll
      for (int i = 0; i < 2; ++i) {
        atomicAdd(&bnS[hh * 32 + og + 16 * i], sj[i]);
        atomicAdd(&bnQ[hh * 32 + og + 16 * i], qj[i]);
      }
    }
  }
  __syncthreads();
  if (tid < 64) {
    atomicAdd(&bnacc[tid], bnS[tid]);
    atomicAdd(&bnacc[64 + tid], bnQ[tid]);
  }
}

// ---------------------------------------------------------------------------
// K4: BN finalize -> scale/shift per feature
// ---------------------------------------------------------------------------
__global__ void k_bnfinal(const float* __restrict__ bnacc,
                          const float* __restrict__ gamma,
                          const float* __restrict__ beta,
                          float* __restrict__ bnp) {
  int o = threadIdx.x;  // 64 threads
  float mean = bnacc[o] * (1.0f / NN);
  float var = bnacc[64 + o] * (1.0f / NN) - mean * mean;
  float sc = gamma[o] * rsqrtf(var + 1e-5f);
  bnp[o] = sc;
  bnp[64 + o] = beta[o] - mean * sc;
}

// ---------------------------------------------------------------------------
// K5: h' = relu(bn(h)); z_l = h'@W2_l^T ; z_r = h'@W2_r^T + b2
// Thread map: og = tid&7 (o = og+8i, i<4 -> 32 outs), ng = tid>>3 (n = n0+ng+32j, j<2)
// ---------------------------------------------------------------------------
__global__ __launch_bounds__(256) void k_layer2a(const float* __restrict__ hbuf,
                                                 const float* __restrict__ W2l,
                                                 const float* __restrict__ W2r,
                                                 const float* __restrict__ b2,
                                                 const float* __restrict__ bnp,
                                                 float* __restrict__ zl,
                                                 float* __restrict__ zr) {
  __shared__ float hs[64 * 68];
  __shared__ float ws[32 * 68];
  __shared__ float sc[64], sh[64];
  const int tid = threadIdx.x;
  const int n0 = blockIdx.x * 64;

  if (tid < 64) { sc[tid] = bnp[tid]; sh[tid] = bnp[64 + tid]; }
  for (int i = tid; i < 32 * 16; i += 256) {
    int r = i >> 4, c = i & 15;
    const float* src = (r < 16) ? &W2l[r * 64 + c * 4] : &W2r[(r - 16) * 64 + c * 4];
    *(float4*)&ws[r * 68 + c * 4] = *(const float4*)src;
  }
  __syncthreads();  // sc/sh ready before hs staging uses them

  for (int i = tid; i < 64 * 16; i += 256) {
    int r = i >> 4, c = i & 15;
    int n = n0 + r;
    float4 v = (n < NN) ? *(const float4*)&hbuf[(size_t)n * 64 + c * 4]
                        : make_float4(0.f, 0.f, 0.f, 0.f);
    float4 o;
    o.x = fmaxf(v.x * sc[c * 4 + 0] + sh[c * 4 + 0], 0.f);
    o.y = fmaxf(v.y * sc[c * 4 + 1] + sh[c * 4 + 1], 0.f);
    o.z = fmaxf(v.z * sc[c * 4 + 2] + sh[c * 4 + 2], 0.f);
    o.w = fmaxf(v.w * sc[c * 4 + 3] + sh[c * 4 + 3], 0.f);
    *(float4*)&hs[r * 68 + c * 4] = o;
  }
  __syncthreads();

  const int og = tid & 7, ng = tid >> 3;
  float acc[4][2] = {};
#pragma unroll
  for (int k4 = 0; k4 < 16; ++k4) {
    float4 wv[4], xv[2];
#pragma unroll
    for (int i = 0; i < 4; ++i) wv[i] = *(float4*)&ws[(og + 8 * i) * 68 + k4 * 4];
#pragma unroll
    for (int j = 0; j < 2; ++j) xv[j] = *(float4*)&hs[(ng + 32 * j) * 68 + k4 * 4];
#pragma unroll
    for (int i = 0; i < 4; ++i)
#pragma unroll
      for (int j = 0; j < 2; ++j)
        acc[i][j] += wv[i].x * xv[j].x + wv[i].y * xv[j].y +
                     wv[i].z * xv[j].z + wv[i].w * xv[j].w;
  }

#pragma unroll
  for (int j = 0; j < 2; ++j) {
    int n = n0 + ng + 32 * j;
    if (n < NN) {
#pragma unroll
      for (int i = 0; i < 4; ++i) {
        int o = og + 8 * i;
        if (o < 16)
          zl[(size_t)n * 16 + o] = acc[i][j];
        else
          zr[(size_t)n * 16 + (o - 16)] = acc[i][j] + b2[o - 16];
      }
    }
  }
}

// ---------------------------------------------------------------------------
// K6: per-edge scatter of z_l (16 feats). 16 lanes per edge.
// ---------------------------------------------------------------------------
__global__ __launch_bounds__(256) void k_scatter2(const int* __restrict__ ei,
                                                  const float* __restrict__ zl,
                                                  float* __restrict__ sums2) {
  long long gid = (long long)blockIdx.x * 256 + threadIdx.x;
  int e = (int)(gid >> 4);
  if (e >= NE) return;
  int f = threadIdx.x & 15;
  int s = ei[e];
  int t = ei[NE + e];
  atomicAdd(&sums2[(size_t)t * 16 + f], zl[(size_t)s * 16 + f]);
}

// ---------------------------------------------------------------------------
// K7: out = sums2/max(cnt,1) + z_r
// ---------------------------------------------------------------------------
__global__ __launch_bounds__(256) void k_out(const float* __restrict__ sums2,
                                             const float* __restrict__ zr,
                                             const float* __restrict__ cnt,
                                             float* __restrict__ out) {
  int gid = blockIdx.x * 256 + threadIdx.x;
  if (gid >= NN * 16) return;
  int n = gid >> 4;
  out[gid] = sums2[gid] / fmaxf(cnt[n], 1.0f) + zr[gid];
}

// ---------------------------------------------------------------------------
extern "C" void kernel_launch(void* const* d_in, const int* in_sizes, int n_in,
                              void* d_out, int out_size, void* d_ws, size_t ws_size,
                              hipStream_t stream) {
  const float* x     = (const float*)d_in[0];
  const int*   ei    = (const int*)d_in[1];
  const float* W1l   = (const float*)d_in[2];
  const float* b1    = (const float*)d_in[3];
  const float* W1r   = (const float*)d_in[4];
  const float* gamma = (const float*)d_in[5];
  const float* beta  = (const float*)d_in[6];
  const float* W2l   = (const float*)d_in[7];
  const float* b2    = (const float*)d_in[8];
  const float* W2r   = (const float*)d_in[9];
  float* out = (float*)d_out;
  float* ws  = (float*)d_ws;

  // workspace layout (floats)
  float* sums1 = ws;                 // 6,400,000   [N,64] -> becomes h_pre in-place
  float* cnt   = ws + 6400000;       // 100,000
  float* bnacc = ws + 6500000;       // 128
  float* sums2 = ws + 6500128;       // 1,600,000   [N,16]
  // ---- everything above is zeroed each call: 8,100,128 floats ----
  float* bnp   = ws + 8100128;       // 128 (fully written by k_bnfinal)
  float* yl    = ws + 8100256;       // 6,400,000   [N,64]
  float* zl    = yl;                 // 1,600,000 (reuses yl region after scatter1)
  float* zr    = yl + 1600000;       // 1,600,000

  hipMemsetAsync(ws, 0, 8100128 * sizeof(float), stream);

  const int ntiles = (NN + 63) / 64;  // 1563
  k_gemm1<<<ntiles, 256, 0, stream>>>(x, W1l, yl);
  k_scatter1<<<(NE * 64) / 256, 256, 0, stream>>>(ei, yl, sums1, cnt);
  k_l1finish<<<ntiles, 256, 0, stream>>>(x, W1r, b1, cnt, sums1, bnacc);
  k_bnfinal<<<1, 64, 0, stream>>>(bnacc, gamma, beta, bnp);
  k_layer2a<<<ntiles, 256, 0, stream>>>(sums1, W2l, W2r, b2, bnp, zl, zr);
  k_scatter2<<<(NE * 16) / 256, 256, 0, stream>>>(ei, zl, sums2);
  k_out<<<(NN * 16 + 255) / 256, 256, 0, stream>>>(sums2, zr, cnt, out);
}

// Round 3
// 514.057 us; speedup vs baseline: 1.3069x; 1.3069x over previous
//
#include <hip/hip_runtime.h>

#define NN 100000
#define NE 1600000
// IN_DIM=128, HID_DIM=64, OUT_DIM=16

// workspace word offsets
#define OFF_SUMS1 0          // 6,400,000 f  [N,64]; first 100,000 words overlay hist
#define OFF_YL    6400000    // 6,400,000 f  [N,64]; zl/zr overlay this after agg1
#define OFF_RP    12800000   // 100,000 i    row_ptr (shifted-cursor scheme)
#define OFF_EIDX  12900000   // 1,600,000 i  CSR src indices
#define OFF_BSUM  14500000   // 128 i        scan partials
#define OFF_BNACC 14500128   // 128 f
#define OFF_BNP   14500256   // 128 f

// ---------------------------------------------------------------------------
// CSR build: hist -> 2-level exclusive scan -> fill (shifted cursor)
// After k_fill, rp[n] == end offset of node n; start = (n? rp[n-1] : 0).
// ---------------------------------------------------------------------------
__global__ __launch_bounds__(256) void k_hist(const int* __restrict__ ei,
                                              int* __restrict__ hist) {
  int e = blockIdx.x * 256 + threadIdx.x;
  if (e < NE) atomicAdd(&hist[ei[NE + e]], 1);
}

__global__ __launch_bounds__(1024) void k_scan1(const int* __restrict__ hist,
                                                int* __restrict__ rp,
                                                int* __restrict__ bsum) {
  __shared__ int sd[1024];
  int i = blockIdx.x * 1024 + threadIdx.x;
  int v = (i < NN) ? hist[i] : 0;
  sd[threadIdx.x] = v;
  __syncthreads();
  for (int off = 1; off < 1024; off <<= 1) {
    int t = (threadIdx.x >= off) ? sd[threadIdx.x - off] : 0;
    __syncthreads();
    sd[threadIdx.x] += t;
    __syncthreads();
  }
  if (i < NN) rp[i] = sd[threadIdx.x] - v;  // exclusive (block-local)
  if (threadIdx.x == 1023) bsum[blockIdx.x] = sd[1023];
}

__global__ void k_scan2(int* __restrict__ bsum) {
  if (threadIdx.x == 0) {
    int run = 0;
    for (int b = 0; b < 98; ++b) { int t = bsum[b]; bsum[b] = run; run += t; }
  }
}

__global__ __launch_bounds__(1024) void k_scan3(int* __restrict__ rp,
                                                const int* __restrict__ bsum) {
  int i = blockIdx.x * 1024 + threadIdx.x;
  if (i < NN) rp[i] += bsum[blockIdx.x];
}

__global__ __launch_bounds__(256) void k_fill(const int* __restrict__ ei,
                                              int* __restrict__ rp,
                                              int* __restrict__ eidx) {
  int e = blockIdx.x * 256 + threadIdx.x;
  if (e < NE) {
    int s = ei[e], t = ei[NE + e];
    int slot = atomicAdd(&rp[t], 1);
    eidx[slot] = s;
  }
}

// ---------------------------------------------------------------------------
// K1: y[n][o] = dot(x[n,:128], W1_l[o,:128])
// ---------------------------------------------------------------------------
__global__ __launch_bounds__(256) void k_gemm1(const float* __restrict__ x,
                                               const float* __restrict__ W,
                                               float* __restrict__ y) {
  __shared__ float xs[64 * 132];
  __shared__ float ws[32 * 132];
  const int tid = threadIdx.x;
  const int n0 = blockIdx.x * 64;

  for (int i = tid; i < 64 * 32; i += 256) {
    int r = i >> 5, c = i & 31;
    int n = n0 + r;
    float4 v = (n < NN) ? *(const float4*)&x[(size_t)n * 128 + c * 4]
                        : make_float4(0.f, 0.f, 0.f, 0.f);
    *(float4*)&xs[r * 132 + c * 4] = v;
  }

  const int og = tid & 15, ng = tid >> 4;

  for (int hh = 0; hh < 2; ++hh) {
    __syncthreads();
    for (int i = tid; i < 32 * 32; i += 256) {
      int r = i >> 5, c = i & 31;
      *(float4*)&ws[r * 132 + c * 4] = *(const float4*)&W[(hh * 32 + r) * 128 + c * 4];
    }
    __syncthreads();

    float acc[2][4] = {};
#pragma unroll 2
    for (int k4 = 0; k4 < 32; ++k4) {
      float4 wv[2], xv[4];
#pragma unroll
      for (int i = 0; i < 2; ++i) wv[i] = *(float4*)&ws[(og + 16 * i) * 132 + k4 * 4];
#pragma unroll
      for (int j = 0; j < 4; ++j) xv[j] = *(float4*)&xs[(ng + 16 * j) * 132 + k4 * 4];
#pragma unroll
      for (int i = 0; i < 2; ++i)
#pragma unroll
        for (int j = 0; j < 4; ++j)
          acc[i][j] += wv[i].x * xv[j].x + wv[i].y * xv[j].y +
                       wv[i].z * xv[j].z + wv[i].w * xv[j].w;
    }

#pragma unroll
    for (int j = 0; j < 4; ++j) {
      int n = n0 + ng + 16 * j;
      if (n < NN) {
#pragma unroll
        for (int i = 0; i < 2; ++i)
          y[(size_t)n * 64 + hh * 32 + og + 16 * i] = acc[i][j];
      }
    }
  }
}

// ---------------------------------------------------------------------------
// agg1: sums[n][d] = sum_{k in CSR(n)} y[eidx[k]][d].  Wave per node, lane = feat.
// Edge indices prefetched 64-wide and broadcast via __shfl.
// ---------------------------------------------------------------------------
__global__ __launch_bounds__(256) void k_agg1(const int* __restrict__ rp,
                                              const int* __restrict__ eidx,
                                              const float* __restrict__ y,
                                              float* __restrict__ sums) {
  int node = blockIdx.x * 4 + (threadIdx.x >> 6);
  int lane = threadIdx.x & 63;
  if (node >= NN) return;
  int end = rp[node];
  int start = node ? rp[node - 1] : 0;
  float acc = 0.f;
  for (int k0 = start; k0 < end; k0 += 64) {
    int pre = (k0 + lane < end) ? eidx[k0 + lane] : 0;
    int cnt = min(64, end - k0);
    for (int j = 0; j < cnt; ++j) {
      int s = __shfl(pre, j);
      acc += y[(size_t)s * 64 + lane];
    }
  }
  sums[(size_t)node * 64 + lane] = acc;
}

// ---------------------------------------------------------------------------
// K3: h = sums/deg + b1 + x @ W1_r^T  (in-place) + BN partial sums -> bnacc
// ---------------------------------------------------------------------------
__global__ __launch_bounds__(256) void k_l1finish(const float* __restrict__ x,
                                                  const float* __restrict__ W,
                                                  const float* __restrict__ b1,
                                                  const int* __restrict__ rp,
                                                  float* __restrict__ hbuf,
                                                  float* __restrict__ bnacc) {
  __shared__ float xs[64 * 132];
  __shared__ float ws[32 * 132];
  __shared__ float bnS[64], bnQ[64];
  const int tid = threadIdx.x;
  const int n0 = blockIdx.x * 64;

  if (tid < 64) { bnS[tid] = 0.f; bnQ[tid] = 0.f; }

  for (int i = tid; i < 64 * 32; i += 256) {
    int r = i >> 5, c = i & 31;
    int n = n0 + r;
    float4 v = (n < NN) ? *(const float4*)&x[(size_t)n * 128 + c * 4]
                        : make_float4(0.f, 0.f, 0.f, 0.f);
    *(float4*)&xs[r * 132 + c * 4] = v;
  }

  const int og = tid & 15, ng = tid >> 4;
  int nn[4];
  float invc[4];
#pragma unroll
  for (int j = 0; j < 4; ++j) {
    nn[j] = n0 + ng + 16 * j;
    if (nn[j] < NN) {
      int end = rp[nn[j]];
      int st = nn[j] ? rp[nn[j] - 1] : 0;
      invc[j] = 1.0f / fmaxf((float)(end - st), 1.0f);
    } else {
      invc[j] = 0.f;
    }
  }

  for (int hh = 0; hh < 2; ++hh) {
    __syncthreads();
    for (int i = tid; i < 32 * 32; i += 256) {
      int r = i >> 5, c = i & 31;
      *(float4*)&ws[r * 132 + c * 4] = *(const float4*)&W[(hh * 32 + r) * 128 + c * 4];
    }
    __syncthreads();

    float acc[2][4] = {};
#pragma unroll 2
    for (int k4 = 0; k4 < 32; ++k4) {
      float4 wv[2], xv[4];
#pragma unroll
      for (int i = 0; i < 2; ++i) wv[i] = *(float4*)&ws[(og + 16 * i) * 132 + k4 * 4];
#pragma unroll
      for (int j = 0; j < 4; ++j) xv[j] = *(float4*)&xs[(ng + 16 * j) * 132 + k4 * 4];
#pragma unroll
      for (int i = 0; i < 2; ++i)
#pragma unroll
        for (int j = 0; j < 4; ++j)
          acc[i][j] += wv[i].x * xv[j].x + wv[i].y * xv[j].y +
                       wv[i].z * xv[j].z + wv[i].w * xv[j].w;
    }

    float sj[2] = {0.f, 0.f}, qj[2] = {0.f, 0.f};
#pragma unroll
    for (int j = 0; j < 4; ++j) {
      if (nn[j] < NN) {
#pragma unroll
        for (int i = 0; i < 2; ++i) {
          int o = hh * 32 + og + 16 * i;
          size_t idx = (size_t)nn[j] * 64 + o;
          float v = hbuf[idx] * invc[j] + b1[o] + acc[i][j];
          hbuf[idx] = v;
          sj[i] += v;
          qj[i] += v * v;
        }
      }
    }
#pragma unroll
    for (int i = 0; i < 2; ++i) {
      sj[i] += __shfl_xor(sj[i], 16);
      sj[i] += __shfl_xor(sj[i], 32);
      qj[i] += __shfl_xor(qj[i], 16);
      qj[i] += __shfl_xor(qj[i], 32);
    }
    if (((tid >> 4) & 3) == 0) {
#pragma unroll
      for (int i = 0; i < 2; ++i) {
        atomicAdd(&bnS[hh * 32 + og + 16 * i], sj[i]);
        atomicAdd(&bnQ[hh * 32 + og + 16 * i], qj[i]);
      }
    }
  }
  __syncthreads();
  if (tid < 64) {
    atomicAdd(&bnacc[tid], bnS[tid]);
    atomicAdd(&bnacc[64 + tid], bnQ[tid]);
  }
}

// ---------------------------------------------------------------------------
// K4: BN finalize -> per-feature scale/shift
// ---------------------------------------------------------------------------
__global__ void k_bnfinal(const float* __restrict__ bnacc,
                          const float* __restrict__ gamma,
                          const float* __restrict__ beta,
                          float* __restrict__ bnp) {
  int o = threadIdx.x;  // 64 threads
  float mean = bnacc[o] * (1.0f / NN);
  float var = bnacc[64 + o] * (1.0f / NN) - mean * mean;
  float sc = gamma[o] * rsqrtf(var + 1e-5f);
  bnp[o] = sc;
  bnp[64 + o] = beta[o] - mean * sc;
}

// ---------------------------------------------------------------------------
// K5: h' = relu(bn(h)); zl = h'@W2_l^T ; zr = h'@W2_r^T + b2
// ---------------------------------------------------------------------------
__global__ __launch_bounds__(256) void k_layer2a(const float* __restrict__ hbuf,
                                                 const float* __restrict__ W2l,
                                                 const float* __restrict__ W2r,
                                                 const float* __restrict__ b2,
                                                 const float* __restrict__ bnp,
                                                 float* __restrict__ zl,
                                                 float* __restrict__ zr) {
  __shared__ float hs[64 * 68];
  __shared__ float ws[32 * 68];
  __shared__ float sc[64], sh[64];
  const int tid = threadIdx.x;
  const int n0 = blockIdx.x * 64;

  if (tid < 64) { sc[tid] = bnp[tid]; sh[tid] = bnp[64 + tid]; }
  for (int i = tid; i < 32 * 16; i += 256) {
    int r = i >> 4, c = i & 15;
    const float* src = (r < 16) ? &W2l[r * 64 + c * 4] : &W2r[(r - 16) * 64 + c * 4];
    *(float4*)&ws[r * 68 + c * 4] = *(const float4*)src;
  }
  __syncthreads();

  for (int i = tid; i < 64 * 16; i += 256) {
    int r = i >> 4, c = i & 15;
    int n = n0 + r;
    float4 v = (n < NN) ? *(const float4*)&hbuf[(size_t)n * 64 + c * 4]
                        : make_float4(0.f, 0.f, 0.f, 0.f);
    float4 o;
    o.x = fmaxf(v.x * sc[c * 4 + 0] + sh[c * 4 + 0], 0.f);
    o.y = fmaxf(v.y * sc[c * 4 + 1] + sh[c * 4 + 1], 0.f);
    o.z = fmaxf(v.z * sc[c * 4 + 2] + sh[c * 4 + 2], 0.f);
    o.w = fmaxf(v.w * sc[c * 4 + 3] + sh[c * 4 + 3], 0.f);
    *(float4*)&hs[r * 68 + c * 4] = o;
  }
  __syncthreads();

  const int og = tid & 7, ng = tid >> 3;
  float acc[4][2] = {};
#pragma unroll
  for (int k4 = 0; k4 < 16; ++k4) {
    float4 wv[4], xv[2];
#pragma unroll
    for (int i = 0; i < 4; ++i) wv[i] = *(float4*)&ws[(og + 8 * i) * 68 + k4 * 4];
#pragma unroll
    for (int j = 0; j < 2; ++j) xv[j] = *(float4*)&hs[(ng + 32 * j) * 68 + k4 * 4];
#pragma unroll
    for (int i = 0; i < 4; ++i)
#pragma unroll
      for (int j = 0; j < 2; ++j)
        acc[i][j] += wv[i].x * xv[j].x + wv[i].y * xv[j].y +
                     wv[i].z * xv[j].z + wv[i].w * xv[j].w;
  }

#pragma unroll
  for (int j = 0; j < 2; ++j) {
    int n = n0 + ng + 32 * j;
    if (n < NN) {
#pragma unroll
      for (int i = 0; i < 4; ++i) {
        int o = og + 8 * i;
        if (o < 16)
          zl[(size_t)n * 16 + o] = acc[i][j];
        else
          zr[(size_t)n * 16 + (o - 16)] = acc[i][j] + b2[o - 16];
      }
    }
  }
}

// ---------------------------------------------------------------------------
// agg2 + out: out[n][f] = (sum_{k in CSR(n)} zl[eidx[k]][f]) / deg + zr[n][f]
// Wave per node; lane = j*16+f covers 4 edges x 16 feats; shfl_xor reduce over j.
// ---------------------------------------------------------------------------
__global__ __launch_bounds__(256) void k_agg2(const int* __restrict__ rp,
                                              const int* __restrict__ eidx,
                                              const float* __restrict__ zl,
                                              const float* __restrict__ zr,
                                              float* __restrict__ out) {
  int node = blockIdx.x * 4 + (threadIdx.x >> 6);
  int lane = threadIdx.x & 63;
  if (node >= NN) return;
  int f = lane & 15, jj = lane >> 4;
  int end = rp[node];
  int start = node ? rp[node - 1] : 0;
  float acc = 0.f;
  for (int k = start + jj; k < end; k += 4)
    acc += zl[(size_t)eidx[k] * 16 + f];
  acc += __shfl_xor(acc, 16);
  acc += __shfl_xor(acc, 32);
  if (jj == 0) {
    float invc = 1.0f / fmaxf((float)(end - start), 1.0f);
    out[(size_t)node * 16 + f] = acc * invc + zr[(size_t)node * 16 + f];
  }
}

// ---------------------------------------------------------------------------
extern "C" void kernel_launch(void* const* d_in, const int* in_sizes, int n_in,
                              void* d_out, int out_size, void* d_ws, size_t ws_size,
                              hipStream_t stream) {
  const float* x     = (const float*)d_in[0];
  const int*   ei    = (const int*)d_in[1];
  const float* W1l   = (const float*)d_in[2];
  const float* b1    = (const float*)d_in[3];
  const float* W1r   = (const float*)d_in[4];
  const float* gamma = (const float*)d_in[5];
  const float* beta  = (const float*)d_in[6];
  const float* W2l   = (const float*)d_in[7];
  const float* b2    = (const float*)d_in[8];
  const float* W2r   = (const float*)d_in[9];
  float* out = (float*)d_out;
  float* ws  = (float*)d_ws;

  float* sums1 = ws + OFF_SUMS1;          // [N,64] -> h in-place
  float* yl    = ws + OFF_YL;             // [N,64]
  float* zl    = yl;                      // [N,16] overlay (yl dead after agg1)
  float* zr    = yl + 1600000;            // [N,16]
  int*   rp    = (int*)(ws + OFF_RP);     // row_ptr (shifted-cursor)
  int*   eidx  = (int*)(ws + OFF_EIDX);   // CSR src list
  int*   bsum  = (int*)(ws + OFF_BSUM);
  float* bnacc = ws + OFF_BNACC;
  float* bnp   = ws + OFF_BNP;
  int*   hist  = (int*)(ws + OFF_SUMS1);  // overlays sums1 (dead before agg1)

  hipMemsetAsync(hist, 0, NN * sizeof(int), stream);
  hipMemsetAsync(bnacc, 0, 128 * sizeof(float), stream);

  const int ntiles = (NN + 63) / 64;      // 1563
  k_hist<<<(NE + 255) / 256, 256, 0, stream>>>(ei, hist);
  k_scan1<<<98, 1024, 0, stream>>>(hist, rp, bsum);
  k_scan2<<<1, 64, 0, stream>>>(bsum);
  k_scan3<<<98, 1024, 0, stream>>>(rp, bsum);
  k_fill<<<(NE + 255) / 256, 256, 0, stream>>>(ei, rp, eidx);
  k_gemm1<<<ntiles, 256, 0, stream>>>(x, W1l, yl);
  k_agg1<<<(NN + 3) / 4, 256, 0, stream>>>(rp, eidx, yl, sums1);
  k_l1finish<<<ntiles, 256, 0, stream>>>(x, W1r, b1, rp, sums1, bnacc);
  k_bnfinal<<<1, 64, 0, stream>>>(bnacc, gamma, beta, bnp);
  k_layer2a<<<ntiles, 256, 0, stream>>>(sums1, W2l, W2r, b2, bnp, zl, zr);
  k_agg2<<<(NN + 3) / 4, 256, 0, stream>>>(rp, eidx, zl, zr, out);
}

// Round 6
// 437.368 us; speedup vs baseline: 1.5360x; 1.1753x over previous
//
#include <hip/hip_runtime.h>

#define NN 100000
#define NE 1600000
#define NPB 256                 // nodes per bucket
#define NB 391                  // ceil(NN/NPB)
#define EPB 8192                // edges per partition block

// workspace word offsets
#define OFF_SUMS1  0            // 6,400,000 f  [N,64]; first 100,000 words overlay hist
#define OFF_YL     6400000      // 6,400,000 f  [N,64]; ebuf (int2 x 1.6M) overlays; zl/zr later
#define OFF_RP     12800000     // 100,001 i    row_ptr start offsets (+rp[NN]=NE)
#define OFF_EIDX   12900032     // 1,600,000 i  CSR src indices
#define OFF_BCNT   14500032     // 391 i
#define OFF_BSTART 14500424     // 391 i
#define OFF_BCUR   14500816     // 391 i
#define OFF_BSUM   14501208     // 128 i
#define OFF_BNACC  14501336     // 128 f
#define OFF_BNP    14501464     // 128 f

// ---------------------------------------------------------------------------
// degree histogram
// ---------------------------------------------------------------------------
__global__ __launch_bounds__(256) void k_hist(const int* __restrict__ ei,
                                              int* __restrict__ hist) {
  int e = blockIdx.x * 256 + threadIdx.x;
  if (e < NE) atomicAdd(&hist[ei[NE + e]], 1);
}

// exclusive scan over hist -> rp (2-level)
__global__ __launch_bounds__(1024) void k_scan1(const int* __restrict__ hist,
                                                int* __restrict__ rp,
                                                int* __restrict__ bsum) {
  __shared__ int sd[1024];
  int i = blockIdx.x * 1024 + threadIdx.x;
  int v = (i < NN) ? hist[i] : 0;
  sd[threadIdx.x] = v;
  __syncthreads();
  for (int off = 1; off < 1024; off <<= 1) {
    int t = (threadIdx.x >= off) ? sd[threadIdx.x - off] : 0;
    __syncthreads();
    sd[threadIdx.x] += t;
    __syncthreads();
  }
  if (i < NN) rp[i] = sd[threadIdx.x] - v;  // block-local exclusive
  if (threadIdx.x == 1023) bsum[blockIdx.x] = sd[1023];
}

__global__ void k_scan2(int* __restrict__ bsum) {
  if (threadIdx.x == 0) {
    int run = 0;
    for (int b = 0; b < 98; ++b) { int t = bsum[b]; bsum[b] = run; run += t; }
  }
}

__global__ __launch_bounds__(1024) void k_scan3(int* __restrict__ rp,
                                                const int* __restrict__ bsum) {
  int i = blockIdx.x * 1024 + threadIdx.x;
  if (i < NN) rp[i] += bsum[blockIdx.x];
}

// per-bucket edge counts (reduce hist over each 256-node bucket)
__global__ __launch_bounds__(256) void k_bcnt(const int* __restrict__ hist,
                                              int* __restrict__ bcnt) {
  __shared__ int sd[256];
  int node = blockIdx.x * 256 + threadIdx.x;
  sd[threadIdx.x] = (node < NN) ? hist[node] : 0;
  __syncthreads();
  for (int off = 128; off; off >>= 1) {
    if (threadIdx.x < off) sd[threadIdx.x] += sd[threadIdx.x + off];
    __syncthreads();
  }
  if (threadIdx.x == 0) bcnt[blockIdx.x] = sd[0];
}

// exclusive scan over bcnt -> bstart, bcur; also rp[NN] = NE
__global__ __launch_bounds__(512) void k_bscan(const int* __restrict__ bcnt,
                                               int* __restrict__ bstart,
                                               int* __restrict__ bcur,
                                               int* __restrict__ rp) {
  __shared__ int sd[512];
  int v = (threadIdx.x < NB) ? bcnt[threadIdx.x] : 0;
  sd[threadIdx.x] = v;
  __syncthreads();
  for (int off = 1; off < 512; off <<= 1) {
    int t = (threadIdx.x >= off) ? sd[threadIdx.x - off] : 0;
    __syncthreads();
    sd[threadIdx.x] += t;
    __syncthreads();
  }
  if (threadIdx.x < NB) {
    int s = sd[threadIdx.x] - v;
    bstart[threadIdx.x] = s;
    bcur[threadIdx.x] = s;
  }
  if (threadIdx.x == 0) rp[NN] = NE;
}

// ---------------------------------------------------------------------------
// partition edges into bucket-contiguous regions of ebuf (order within bucket
// arbitrary). Per block: LDS count -> one global reservation per bucket ->
// LDS-cursor placement. Writes per bucket-chunk are contiguous.
// ---------------------------------------------------------------------------
__global__ __launch_bounds__(256) void k_part(const int* __restrict__ ei,
                                              int* __restrict__ bcur,
                                              int2* __restrict__ ebuf) {
  __shared__ int cnt[NB], gstart[NB], cur[NB];
  int e0 = blockIdx.x * EPB;
  int e1 = min(e0 + EPB, NE);
  for (int i = threadIdx.x; i < NB; i += 256) cnt[i] = 0;
  __syncthreads();
  for (int e = e0 + threadIdx.x; e < e1; e += 256)
    atomicAdd(&cnt[ei[NE + e] >> 8], 1);
  __syncthreads();
  for (int b = threadIdx.x; b < NB; b += 256) {
    int c = cnt[b];
    gstart[b] = c ? atomicAdd(&bcur[b], c) : 0;
    cur[b] = 0;
  }
  __syncthreads();
  for (int e = e0 + threadIdx.x; e < e1; e += 256) {
    int s = ei[e], t = ei[NE + e];
    int b = t >> 8;
    int r = atomicAdd(&cur[b], 1);
    ebuf[gstart[b] + r] = make_int2(s, t);
  }
}

// ---------------------------------------------------------------------------
// CSR fill, one block per bucket: LDS cursors, eidx writes stay in one 32KB
// region owned by this CU's XCD -> each line written back once.
// ---------------------------------------------------------------------------
__global__ __launch_bounds__(256) void k_fill2(const int* __restrict__ rp,
                                               const int* __restrict__ bstart,
                                               const int* __restrict__ bcur,
                                               const int2* __restrict__ ebuf,
                                               int* __restrict__ eidx) {
  __shared__ int cur[NPB];
  int b = blockIdx.x;
  int node0 = b << 8;
  int nnode = min(NPB, NN - node0);
  for (int i = threadIdx.x; i < nnode; i += 256) cur[i] = rp[node0 + i];
  __syncthreads();
  int k1 = bcur[b];
  for (int k = bstart[b] + threadIdx.x; k < k1; k += 256) {
    int2 r = ebuf[k];
    int slot = atomicAdd(&cur[r.y - node0], 1);
    eidx[slot] = r.x;
  }
}

// ---------------------------------------------------------------------------
// K1: y[n][o] = dot(x[n,:128], W1_l[o,:128])
// ---------------------------------------------------------------------------
__global__ __launch_bounds__(256) void k_gemm1(const float* __restrict__ x,
                                               const float* __restrict__ W,
                                               float* __restrict__ y) {
  __shared__ float xs[64 * 132];
  __shared__ float ws[32 * 132];
  const int tid = threadIdx.x;
  const int n0 = blockIdx.x * 64;

  for (int i = tid; i < 64 * 32; i += 256) {
    int r = i >> 5, c = i & 31;
    int n = n0 + r;
    float4 v = (n < NN) ? *(const float4*)&x[(size_t)n * 128 + c * 4]
                        : make_float4(0.f, 0.f, 0.f, 0.f);
    *(float4*)&xs[r * 132 + c * 4] = v;
  }

  const int og = tid & 15, ng = tid >> 4;

  for (int hh = 0; hh < 2; ++hh) {
    __syncthreads();
    for (int i = tid; i < 32 * 32; i += 256) {
      int r = i >> 5, c = i & 31;
      *(float4*)&ws[r * 132 + c * 4] = *(const float4*)&W[(hh * 32 + r) * 128 + c * 4];
    }
    __syncthreads();

    float acc[2][4] = {};
#pragma unroll 2
    for (int k4 = 0; k4 < 32; ++k4) {
      float4 wv[2], xv[4];
#pragma unroll
      for (int i = 0; i < 2; ++i) wv[i] = *(float4*)&ws[(og + 16 * i) * 132 + k4 * 4];
#pragma unroll
      for (int j = 0; j < 4; ++j) xv[j] = *(float4*)&xs[(ng + 16 * j) * 132 + k4 * 4];
#pragma unroll
      for (int i = 0; i < 2; ++i)
#pragma unroll
        for (int j = 0; j < 4; ++j)
          acc[i][j] += wv[i].x * xv[j].x + wv[i].y * xv[j].y +
                       wv[i].z * xv[j].z + wv[i].w * xv[j].w;
    }

#pragma unroll
    for (int j = 0; j < 4; ++j) {
      int n = n0 + ng + 16 * j;
      if (n < NN) {
#pragma unroll
        for (int i = 0; i < 2; ++i)
          y[(size_t)n * 64 + hh * 32 + og + 16 * i] = acc[i][j];
      }
    }
  }
}

// ---------------------------------------------------------------------------
// agg1: sums[n][d] = sum_{k in CSR(n)} y[eidx[k]][d].  Wave per node, lane = feat.
// ---------------------------------------------------------------------------
__global__ __launch_bounds__(256) void k_agg1(const int* __restrict__ rp,
                                              const int* __restrict__ eidx,
                                              const float* __restrict__ y,
                                              float* __restrict__ sums) {
  int node = blockIdx.x * 4 + (threadIdx.x >> 6);
  int lane = threadIdx.x & 63;
  if (node >= NN) return;
  int start = rp[node];
  int end = rp[node + 1];
  float acc = 0.f;
  for (int k0 = start; k0 < end; k0 += 64) {
    int pre = (k0 + lane < end) ? eidx[k0 + lane] : 0;
    int cnt = min(64, end - k0);
    for (int j = 0; j < cnt; ++j) {
      int s = __shfl(pre, j);
      acc += y[(size_t)s * 64 + lane];
    }
  }
  sums[(size_t)node * 64 + lane] = acc;
}

// ---------------------------------------------------------------------------
// K3: h = sums/deg + b1 + x @ W1_r^T (in-place) + BN partial sums -> bnacc
// ---------------------------------------------------------------------------
__global__ __launch_bounds__(256) void k_l1finish(const float* __restrict__ x,
                                                  const float* __restrict__ W,
                                                  const float* __restrict__ b1,
                                                  const int* __restrict__ rp,
                                                  float* __restrict__ hbuf,
                                                  float* __restrict__ bnacc) {
  __shared__ float xs[64 * 132];
  __shared__ float ws[32 * 132];
  __shared__ float bnS[64], bnQ[64];
  const int tid = threadIdx.x;
  const int n0 = blockIdx.x * 64;

  if (tid < 64) { bnS[tid] = 0.f; bnQ[tid] = 0.f; }

  for (int i = tid; i < 64 * 32; i += 256) {
    int r = i >> 5, c = i & 31;
    int n = n0 + r;
    float4 v = (n < NN) ? *(const float4*)&x[(size_t)n * 128 + c * 4]
                        : make_float4(0.f, 0.f, 0.f, 0.f);
    *(float4*)&xs[r * 132 + c * 4] = v;
  }

  const int og = tid & 15, ng = tid >> 4;
  int nn[4];
  float invc[4];
#pragma unroll
  for (int j = 0; j < 4; ++j) {
    nn[j] = n0 + ng + 16 * j;
    if (nn[j] < NN) {
      int st = rp[nn[j]], en = rp[nn[j] + 1];
      invc[j] = 1.0f / fmaxf((float)(en - st), 1.0f);
    } else {
      invc[j] = 0.f;
    }
  }

  for (int hh = 0; hh < 2; ++hh) {
    __syncthreads();
    for (int i = tid; i < 32 * 32; i += 256) {
      int r = i >> 5, c = i & 31;
      *(float4*)&ws[r * 132 + c * 4] = *(const float4*)&W[(hh * 32 + r) * 128 + c * 4];
    }
    __syncthreads();

    float acc[2][4] = {};
#pragma unroll 2
    for (int k4 = 0; k4 < 32; ++k4) {
      float4 wv[2], xv[4];
#pragma unroll
      for (int i = 0; i < 2; ++i) wv[i] = *(float4*)&ws[(og + 16 * i) * 132 + k4 * 4];
#pragma unroll
      for (int j = 0; j < 4; ++j) xv[j] = *(float4*)&xs[(ng + 16 * j) * 132 + k4 * 4];
#pragma unroll
      for (int i = 0; i < 2; ++i)
#pragma unroll
        for (int j = 0; j < 4; ++j)
          acc[i][j] += wv[i].x * xv[j].x + wv[i].y * xv[j].y +
                       wv[i].z * xv[j].z + wv[i].w * xv[j].w;
    }

    float sj[2] = {0.f, 0.f}, qj[2] = {0.f, 0.f};
#pragma unroll
    for (int j = 0; j < 4; ++j) {
      if (nn[j] < NN) {
#pragma unroll
        for (int i = 0; i < 2; ++i) {
          int o = hh * 32 + og + 16 * i;
          size_t idx = (size_t)nn[j] * 64 + o;
          float v = hbuf[idx] * invc[j] + b1[o] + acc[i][j];
          hbuf[idx] = v;
          sj[i] += v;
          qj[i] += v * v;
        }
      }
    }
#pragma unroll
    for (int i = 0; i < 2; ++i) {
      sj[i] += __shfl_xor(sj[i], 16);
      sj[i] += __shfl_xor(sj[i], 32);
      qj[i] += __shfl_xor(qj[i], 16);
      qj[i] += __shfl_xor(qj[i], 32);
    }
    if (((tid >> 4) & 3) == 0) {
#pragma unroll
      for (int i = 0; i < 2; ++i) {
        atomicAdd(&bnS[hh * 32 + og + 16 * i], sj[i]);
        atomicAdd(&bnQ[hh * 32 + og + 16 * i], qj[i]);
      }
    }
  }
  __syncthreads();
  if (tid < 64) {
    atomicAdd(&bnacc[tid], bnS[tid]);
    atomicAdd(&bnacc[64 + tid], bnQ[tid]);
  }
}

// ---------------------------------------------------------------------------
__global__ void k_bnfinal(const float* __restrict__ bnacc,
                          const float* __restrict__ gamma,
                          const float* __restrict__ beta,
                          float* __restrict__ bnp) {
  int o = threadIdx.x;  // 64 threads
  float mean = bnacc[o] * (1.0f / NN);
  float var = bnacc[64 + o] * (1.0f / NN) - mean * mean;
  float sc = gamma[o] * rsqrtf(var + 1e-5f);
  bnp[o] = sc;
  bnp[64 + o] = beta[o] - mean * sc;
}

// ---------------------------------------------------------------------------
// K5: h' = relu(bn(h)); zl = h'@W2_l^T ; zr = h'@W2_r^T + b2
// ---------------------------------------------------------------------------
__global__ __launch_bounds__(256) void k_layer2a(const float* __restrict__ hbuf,
                                                 const float* __restrict__ W2l,
                                                 const float* __restrict__ W2r,
                                                 const float* __restrict__ b2,
                                                 const float* __restrict__ bnp,
                                                 float* __restrict__ zl,
                                                 float* __restrict__ zr) {
  __shared__ float hs[64 * 68];
  __shared__ float ws[32 * 68];
  __shared__ float sc[64], sh[64];
  const int tid = threadIdx.x;
  const int n0 = blockIdx.x * 64;

  if (tid < 64) { sc[tid] = bnp[tid]; sh[tid] = bnp[64 + tid]; }
  for (int i = tid; i < 32 * 16; i += 256) {
    int r = i >> 4, c = i & 15;
    const float* src = (r < 16) ? &W2l[r * 64 + c * 4] : &W2r[(r - 16) * 64 + c * 4];
    *(float4*)&ws[r * 68 + c * 4] = *(const float4*)src;
  }
  __syncthreads();

  for (int i = tid; i < 64 * 16; i += 256) {
    int r = i >> 4, c = i & 15;
    int n = n0 + r;
    float4 v = (n < NN) ? *(const float4*)&hbuf[(size_t)n * 64 + c * 4]
                        : make_float4(0.f, 0.f, 0.f, 0.f);
    float4 o;
    o.x = fmaxf(v.x * sc[c * 4 + 0] + sh[c * 4 + 0], 0.f);
    o.y = fmaxf(v.y * sc[c * 4 + 1] + sh[c * 4 + 1], 0.f);
    o.z = fmaxf(v.z * sc[c * 4 + 2] + sh[c * 4 + 2], 0.f);
    o.w = fmaxf(v.w * sc[c * 4 + 3] + sh[c * 4 + 3], 0.f);
    *(float4*)&hs[r * 68 + c * 4] = o;
  }
  __syncthreads();

  const int og = tid & 7, ng = tid >> 3;
  float acc[4][2] = {};
#pragma unroll
  for (int k4 = 0; k4 < 16; ++k4) {
    float4 wv[4], xv[2];
#pragma unroll
    for (int i = 0; i < 4; ++i) wv[i] = *(float4*)&ws[(og + 8 * i) * 68 + k4 * 4];
#pragma unroll
    for (int j = 0; j < 2; ++j) xv[j] = *(float4*)&hs[(ng + 32 * j) * 68 + k4 * 4];
#pragma unroll
    for (int i = 0; i < 4; ++i)
#pragma unroll
      for (int j = 0; j < 2; ++j)
        acc[i][j] += wv[i].x * xv[j].x + wv[i].y * xv[j].y +
                     wv[i].z * xv[j].z + wv[i].w * xv[j].w;
  }

#pragma unroll
  for (int j = 0; j < 2; ++j) {
    int n = n0 + ng + 32 * j;
    if (n < NN) {
#pragma unroll
      for (int i = 0; i < 4; ++i) {
        int o = og + 8 * i;
        if (o < 16)
          zl[(size_t)n * 16 + o] = acc[i][j];
        else
          zr[(size_t)n * 16 + (o - 16)] = acc[i][j] + b2[o - 16];
      }
    }
  }
}

// ---------------------------------------------------------------------------
// agg2 + out
// ---------------------------------------------------------------------------
__global__ __launch_bounds__(256) void k_agg2(const int* __restrict__ rp,
                                              const int* __restrict__ eidx,
                                              const float* __restrict__ zl,
                                              const float* __restrict__ zr,
                                              float* __restrict__ out) {
  int node = blockIdx.x * 4 + (threadIdx.x >> 6);
  int lane = threadIdx.x & 63;
  if (node >= NN) return;
  int f = lane & 15, jj = lane >> 4;
  int start = rp[node];
  int end = rp[node + 1];
  float acc = 0.f;
  for (int k = start + jj; k < end; k += 4)
    acc += zl[(size_t)eidx[k] * 16 + f];
  acc += __shfl_xor(acc, 16);
  acc += __shfl_xor(acc, 32);
  if (jj == 0) {
    float invc = 1.0f / fmaxf((float)(end - start), 1.0f);
    out[(size_t)node * 16 + f] = acc * invc + zr[(size_t)node * 16 + f];
  }
}

// ---------------------------------------------------------------------------
extern "C" void kernel_launch(void* const* d_in, const int* in_sizes, int n_in,
                              void* d_out, int out_size, void* d_ws, size_t ws_size,
                              hipStream_t stream) {
  const float* x     = (const float*)d_in[0];
  const int*   ei    = (const int*)d_in[1];
  const float* W1l   = (const float*)d_in[2];
  const float* b1    = (const float*)d_in[3];
  const float* W1r   = (const float*)d_in[4];
  const float* gamma = (const float*)d_in[5];
  const float* beta  = (const float*)d_in[6];
  const float* W2l   = (const float*)d_in[7];
  const float* b2    = (const float*)d_in[8];
  const float* W2r   = (const float*)d_in[9];
  float* out = (float*)d_out;
  float* ws  = (float*)d_ws;

  float* sums1  = ws + OFF_SUMS1;           // [N,64] -> h in-place
  float* yl     = ws + OFF_YL;              // [N,64]
  int2*  ebuf   = (int2*)(ws + OFF_YL);     // overlays yl (dead before gemm1)
  float* zl     = yl;                       // [N,16] overlay (yl dead after agg1)
  float* zr     = yl + 1600000;             // [N,16]
  int*   rp     = (int*)(ws + OFF_RP);      // NN+1 start offsets
  int*   eidx   = (int*)(ws + OFF_EIDX);
  int*   bcnt   = (int*)(ws + OFF_BCNT);
  int*   bstart = (int*)(ws + OFF_BSTART);
  int*   bcur   = (int*)(ws + OFF_BCUR);
  int*   bsum   = (int*)(ws + OFF_BSUM);
  float* bnacc  = ws + OFF_BNACC;
  float* bnp    = ws + OFF_BNP;
  int*   hist   = (int*)(ws + OFF_SUMS1);   // overlays sums1 (dead after k_bcnt)

  hipMemsetAsync(hist, 0, NN * sizeof(int), stream);
  hipMemsetAsync(bnacc, 0, 128 * sizeof(float), stream);

  const int ntiles = (NN + 63) / 64;        // 1563
  k_hist<<<(NE + 255) / 256, 256, 0, stream>>>(ei, hist);
  k_scan1<<<98, 1024, 0, stream>>>(hist, rp, bsum);
  k_scan2<<<1, 64, 0, stream>>>(bsum);
  k_scan3<<<98, 1024, 0, stream>>>(rp, bsum);
  k_bcnt<<<NB, 256, 0, stream>>>(hist, bcnt);
  k_bscan<<<1, 512, 0, stream>>>(bcnt, bstart, bcur, rp);
  k_part<<<(NE + EPB - 1) / EPB, 256, 0, stream>>>(ei, bcur, ebuf);
  k_fill2<<<NB, 256, 0, stream>>>(rp, bstart, bcur, ebuf, eidx);
  k_gemm1<<<ntiles, 256, 0, stream>>>(x, W1l, yl);
  k_agg1<<<(NN + 3) / 4, 256, 0, stream>>>(rp, eidx, yl, sums1);
  k_l1finish<<<ntiles, 256, 0, stream>>>(x, W1r, b1, rp, sums1, bnacc);
  k_bnfinal<<<1, 64, 0, stream>>>(bnacc, gamma, beta, bnp);
  k_layer2a<<<ntiles, 256, 0, stream>>>(sums1, W2l, W2r, b2, bnp, zl, zr);
  k_agg2<<<(NN + 3) / 4, 256, 0, stream>>>(rp, eidx, zl, zr, out);
}

// Round 7
// 368.314 us; speedup vs baseline: 1.8240x; 1.1875x over previous
//
#include <hip/hip_runtime.h>

#define NN 100000
#define NE 1600000
#define NPB 256                 // nodes per bucket
#define NB 391                  // ceil(NN/NPB)
#define EPB 8192                // edges per partition block

// workspace word offsets
#define OFF_SUMS1  0            // 6,400,000 f  [N,64]; first 100,000 words overlay hist
#define OFF_YL     6400000      // region: ebuf(int2 x1.6M) -> yl(bf16 [N,64]) -> zl(bf16)+zr(f32)
#define OFF_RP     12800000     // 100,001 i    row_ptr start offsets (+rp[NN]=NE)
#define OFF_EIDX   12900032     // 1,600,000 i  CSR src indices
#define OFF_BCNT   14500032     // 391 i
#define OFF_BSTART 14500424     // 391 i
#define OFF_BCUR   14500816     // 391 i
#define OFF_BSUM   14501208     // 128 i
#define OFF_BNACC  14501336     // 128 f
#define OFF_BNP    14501464     // 128 f

__device__ __forceinline__ ushort f2bf(float f) {   // RNE f32 -> bf16
  unsigned u = __float_as_uint(f);
  u += 0x7fffu + ((u >> 16) & 1);
  return (ushort)(u >> 16);
}
#define BFLO(u) __uint_as_float(((u) & 0xffffu) << 16)
#define BFHI(u) __uint_as_float((u) & 0xffff0000u)

// ---------------------------------------------------------------------------
// degree histogram
// ---------------------------------------------------------------------------
__global__ __launch_bounds__(256) void k_hist(const int* __restrict__ ei,
                                              int* __restrict__ hist) {
  int e = blockIdx.x * 256 + threadIdx.x;
  if (e < NE) atomicAdd(&hist[ei[NE + e]], 1);
}

// exclusive scan over hist -> rp (2-level)
__global__ __launch_bounds__(1024) void k_scan1(const int* __restrict__ hist,
                                                int* __restrict__ rp,
                                                int* __restrict__ bsum) {
  __shared__ int sd[1024];
  int i = blockIdx.x * 1024 + threadIdx.x;
  int v = (i < NN) ? hist[i] : 0;
  sd[threadIdx.x] = v;
  __syncthreads();
  for (int off = 1; off < 1024; off <<= 1) {
    int t = (threadIdx.x >= off) ? sd[threadIdx.x - off] : 0;
    __syncthreads();
    sd[threadIdx.x] += t;
    __syncthreads();
  }
  if (i < NN) rp[i] = sd[threadIdx.x] - v;  // block-local exclusive
  if (threadIdx.x == 1023) bsum[blockIdx.x] = sd[1023];
}

__global__ void k_scan2(int* __restrict__ bsum) {
  if (threadIdx.x == 0) {
    int run = 0;
    for (int b = 0; b < 98; ++b) { int t = bsum[b]; bsum[b] = run; run += t; }
  }
}

__global__ __launch_bounds__(1024) void k_scan3(int* __restrict__ rp,
                                                const int* __restrict__ bsum) {
  int i = blockIdx.x * 1024 + threadIdx.x;
  if (i < NN) rp[i] += bsum[blockIdx.x];
}

// per-bucket edge counts
__global__ __launch_bounds__(256) void k_bcnt(const int* __restrict__ hist,
                                              int* __restrict__ bcnt) {
  __shared__ int sd[256];
  int node = blockIdx.x * 256 + threadIdx.x;
  sd[threadIdx.x] = (node < NN) ? hist[node] : 0;
  __syncthreads();
  for (int off = 128; off; off >>= 1) {
    if (threadIdx.x < off) sd[threadIdx.x] += sd[threadIdx.x + off];
    __syncthreads();
  }
  if (threadIdx.x == 0) bcnt[blockIdx.x] = sd[0];
}

// exclusive scan over bcnt -> bstart, bcur; also rp[NN] = NE
__global__ __launch_bounds__(512) void k_bscan(const int* __restrict__ bcnt,
                                               int* __restrict__ bstart,
                                               int* __restrict__ bcur,
                                               int* __restrict__ rp) {
  __shared__ int sd[512];
  int v = (threadIdx.x < NB) ? bcnt[threadIdx.x] : 0;
  sd[threadIdx.x] = v;
  __syncthreads();
  for (int off = 1; off < 512; off <<= 1) {
    int t = (threadIdx.x >= off) ? sd[threadIdx.x - off] : 0;
    __syncthreads();
    sd[threadIdx.x] += t;
    __syncthreads();
  }
  if (threadIdx.x < NB) {
    int s = sd[threadIdx.x] - v;
    bstart[threadIdx.x] = s;
    bcur[threadIdx.x] = s;
  }
  if (threadIdx.x == 0) rp[NN] = NE;
}

// ---------------------------------------------------------------------------
// partition edges into bucket-contiguous regions of ebuf
// ---------------------------------------------------------------------------
__global__ __launch_bounds__(256) void k_part(const int* __restrict__ ei,
                                              int* __restrict__ bcur,
                                              int2* __restrict__ ebuf) {
  __shared__ int cnt[NB], gstart[NB], cur[NB];
  int e0 = blockIdx.x * EPB;
  int e1 = min(e0 + EPB, NE);
  for (int i = threadIdx.x; i < NB; i += 256) cnt[i] = 0;
  __syncthreads();
  for (int e = e0 + threadIdx.x; e < e1; e += 256)
    atomicAdd(&cnt[ei[NE + e] >> 8], 1);
  __syncthreads();
  for (int b = threadIdx.x; b < NB; b += 256) {
    int c = cnt[b];
    gstart[b] = c ? atomicAdd(&bcur[b], c) : 0;
    cur[b] = 0;
  }
  __syncthreads();
  for (int e = e0 + threadIdx.x; e < e1; e += 256) {
    int s = ei[e], t = ei[NE + e];
    int b = t >> 8;
    int r = atomicAdd(&cur[b], 1);
    ebuf[gstart[b] + r] = make_int2(s, t);
  }
}

// ---------------------------------------------------------------------------
// CSR fill, one block per bucket (LDS cursors, localized eidx writes)
// ---------------------------------------------------------------------------
__global__ __launch_bounds__(256) void k_fill2(const int* __restrict__ rp,
                                               const int* __restrict__ bstart,
                                               const int* __restrict__ bcur,
                                               const int2* __restrict__ ebuf,
                                               int* __restrict__ eidx) {
  __shared__ int cur[NPB];
  int b = blockIdx.x;
  int node0 = b << 8;
  int nnode = min(NPB, NN - node0);
  for (int i = threadIdx.x; i < nnode; i += 256) cur[i] = rp[node0 + i];
  __syncthreads();
  int k1 = bcur[b];
  for (int k = bstart[b] + threadIdx.x; k < k1; k += 256) {
    int2 r = ebuf[k];
    int slot = atomicAdd(&cur[r.y - node0], 1);
    eidx[slot] = r.x;
  }
}

// ---------------------------------------------------------------------------
// K1: y[n][o] = dot(x[n,:128], W1_l[o,:128]) -> bf16
// ---------------------------------------------------------------------------
__global__ __launch_bounds__(256) void k_gemm1(const float* __restrict__ x,
                                               const float* __restrict__ W,
                                               ushort* __restrict__ y) {
  __shared__ float xs[64 * 132];
  __shared__ float ws[32 * 132];
  const int tid = threadIdx.x;
  const int n0 = blockIdx.x * 64;

  for (int i = tid; i < 64 * 32; i += 256) {
    int r = i >> 5, c = i & 31;
    int n = n0 + r;
    float4 v = (n < NN) ? *(const float4*)&x[(size_t)n * 128 + c * 4]
                        : make_float4(0.f, 0.f, 0.f, 0.f);
    *(float4*)&xs[r * 132 + c * 4] = v;
  }

  const int og = tid & 15, ng = tid >> 4;

  for (int hh = 0; hh < 2; ++hh) {
    __syncthreads();
    for (int i = tid; i < 32 * 32; i += 256) {
      int r = i >> 5, c = i & 31;
      *(float4*)&ws[r * 132 + c * 4] = *(const float4*)&W[(hh * 32 + r) * 128 + c * 4];
    }
    __syncthreads();

    float acc[2][4] = {};
#pragma unroll 2
    for (int k4 = 0; k4 < 32; ++k4) {
      float4 wv[2], xv[4];
#pragma unroll
      for (int i = 0; i < 2; ++i) wv[i] = *(float4*)&ws[(og + 16 * i) * 132 + k4 * 4];
#pragma unroll
      for (int j = 0; j < 4; ++j) xv[j] = *(float4*)&xs[(ng + 16 * j) * 132 + k4 * 4];
#pragma unroll
      for (int i = 0; i < 2; ++i)
#pragma unroll
        for (int j = 0; j < 4; ++j)
          acc[i][j] += wv[i].x * xv[j].x + wv[i].y * xv[j].y +
                       wv[i].z * xv[j].z + wv[i].w * xv[j].w;
    }

#pragma unroll
    for (int j = 0; j < 4; ++j) {
      int n = n0 + ng + 16 * j;
      if (n < NN) {
#pragma unroll
        for (int i = 0; i < 2; ++i)
          y[(size_t)n * 64 + hh * 32 + og + 16 * i] = f2bf(acc[i][j]);
      }
    }
  }
}

// ---------------------------------------------------------------------------
// agg1: sums[n][d] = sum_{k in CSR(n)} y_bf16[eidx[k]][d].
// Wave per node; 4 edges in parallel (sub = lane>>4), lane&15 covers 4 feats
// via one 8B uint2 load (16 lanes x 8B = full 128B row).
// ---------------------------------------------------------------------------
__global__ __launch_bounds__(256) void k_agg1(const int* __restrict__ rp,
                                              const int* __restrict__ eidx,
                                              const ushort* __restrict__ y,
                                              float* __restrict__ sums) {
  int node = blockIdx.x * 4 + (threadIdx.x >> 6);
  int lane = threadIdx.x & 63;
  if (node >= NN) return;
  int start = rp[node];
  int end = rp[node + 1];
  int f4 = lane & 15;         // feats 4*f4 .. 4*f4+3
  int sub = lane >> 4;        // edge subgroup 0..3
  float a0 = 0.f, a1 = 0.f, a2 = 0.f, a3 = 0.f;
  for (int k0 = start; k0 < end; k0 += 64) {
    int pre = (k0 + lane < end) ? eidx[k0 + lane] : 0;
    int cnt = min(64, end - k0);
    for (int g = 0; g * 4 < cnt; ++g) {
      int eslot = g * 4 + sub;
      int s = __shfl(pre, eslot);
      if (eslot < cnt) {
        uint2 v = *(const uint2*)&y[(size_t)s * 64 + f4 * 4];
        a0 += BFLO(v.x); a1 += BFHI(v.x);
        a2 += BFLO(v.y); a3 += BFHI(v.y);
      }
    }
  }
  a0 += __shfl_xor(a0, 16); a0 += __shfl_xor(a0, 32);
  a1 += __shfl_xor(a1, 16); a1 += __shfl_xor(a1, 32);
  a2 += __shfl_xor(a2, 16); a2 += __shfl_xor(a2, 32);
  a3 += __shfl_xor(a3, 16); a3 += __shfl_xor(a3, 32);
  if (sub == 0)
    *(float4*)&sums[(size_t)node * 64 + f4 * 4] = make_float4(a0, a1, a2, a3);
}

// ---------------------------------------------------------------------------
// K3: h = sums/deg + b1 + x @ W1_r^T (in-place) + BN partial sums -> bnacc
// ---------------------------------------------------------------------------
__global__ __launch_bounds__(256) void k_l1finish(const float* __restrict__ x,
                                                  const float* __restrict__ W,
                                                  const float* __restrict__ b1,
                                                  const int* __restrict__ rp,
                                                  float* __restrict__ hbuf,
                                                  float* __restrict__ bnacc) {
  __shared__ float xs[64 * 132];
  __shared__ float ws[32 * 132];
  __shared__ float bnS[64], bnQ[64];
  const int tid = threadIdx.x;
  const int n0 = blockIdx.x * 64;

  if (tid < 64) { bnS[tid] = 0.f; bnQ[tid] = 0.f; }

  for (int i = tid; i < 64 * 32; i += 256) {
    int r = i >> 5, c = i & 31;
    int n = n0 + r;
    float4 v = (n < NN) ? *(const float4*)&x[(size_t)n * 128 + c * 4]
                        : make_float4(0.f, 0.f, 0.f, 0.f);
    *(float4*)&xs[r * 132 + c * 4] = v;
  }

  const int og = tid & 15, ng = tid >> 4;
  int nn[4];
  float invc[4];
#pragma unroll
  for (int j = 0; j < 4; ++j) {
    nn[j] = n0 + ng + 16 * j;
    if (nn[j] < NN) {
      int st = rp[nn[j]], en = rp[nn[j] + 1];
      invc[j] = 1.0f / fmaxf((float)(en - st), 1.0f);
    } else {
      invc[j] = 0.f;
    }
  }

  for (int hh = 0; hh < 2; ++hh) {
    __syncthreads();
    for (int i = tid; i < 32 * 32; i += 256) {
      int r = i >> 5, c = i & 31;
      *(float4*)&ws[r * 132 + c * 4] = *(const float4*)&W[(hh * 32 + r) * 128 + c * 4];
    }
    __syncthreads();

    float acc[2][4] = {};
#pragma unroll 2
    for (int k4 = 0; k4 < 32; ++k4) {
      float4 wv[2], xv[4];
#pragma unroll
      for (int i = 0; i < 2; ++i) wv[i] = *(float4*)&ws[(og + 16 * i) * 132 + k4 * 4];
#pragma unroll
      for (int j = 0; j < 4; ++j) xv[j] = *(float4*)&xs[(ng + 16 * j) * 132 + k4 * 4];
#pragma unroll
      for (int i = 0; i < 2; ++i)
#pragma unroll
        for (int j = 0; j < 4; ++j)
          acc[i][j] += wv[i].x * xv[j].x + wv[i].y * xv[j].y +
                       wv[i].z * xv[j].z + wv[i].w * xv[j].w;
    }

    float sj[2] = {0.f, 0.f}, qj[2] = {0.f, 0.f};
#pragma unroll
    for (int j = 0; j < 4; ++j) {
      if (nn[j] < NN) {
#pragma unroll
        for (int i = 0; i < 2; ++i) {
          int o = hh * 32 + og + 16 * i;
          size_t idx = (size_t)nn[j] * 64 + o;
          float v = hbuf[idx] * invc[j] + b1[o] + acc[i][j];
          hbuf[idx] = v;
          sj[i] += v;
          qj[i] += v * v;
        }
      }
    }
#pragma unroll
    for (int i = 0; i < 2; ++i) {
      sj[i] += __shfl_xor(sj[i], 16);
      sj[i] += __shfl_xor(sj[i], 32);
      qj[i] += __shfl_xor(qj[i], 16);
      qj[i] += __shfl_xor(qj[i], 32);
    }
    if (((tid >> 4) & 3) == 0) {
#pragma unroll
      for (int i = 0; i < 2; ++i) {
        atomicAdd(&bnS[hh * 32 + og + 16 * i], sj[i]);
        atomicAdd(&bnQ[hh * 32 + og + 16 * i], qj[i]);
      }
    }
  }
  __syncthreads();
  if (tid < 64) {
    atomicAdd(&bnacc[tid], bnS[tid]);
    atomicAdd(&bnacc[64 + tid], bnQ[tid]);
  }
}

// ---------------------------------------------------------------------------
__global__ void k_bnfinal(const float* __restrict__ bnacc,
                          const float* __restrict__ gamma,
                          const float* __restrict__ beta,
                          float* __restrict__ bnp) {
  int o = threadIdx.x;  // 64 threads
  float mean = bnacc[o] * (1.0f / NN);
  float var = bnacc[64 + o] * (1.0f / NN) - mean * mean;
  float sc = gamma[o] * rsqrtf(var + 1e-5f);
  bnp[o] = sc;
  bnp[64 + o] = beta[o] - mean * sc;
}

// ---------------------------------------------------------------------------
// K5: h' = relu(bn(h)); zl = h'@W2_l^T (bf16) ; zr = h'@W2_r^T + b2 (f32)
// ---------------------------------------------------------------------------
__global__ __launch_bounds__(256) void k_layer2a(const float* __restrict__ hbuf,
                                                 const float* __restrict__ W2l,
                                                 const float* __restrict__ W2r,
                                                 const float* __restrict__ b2,
                                                 const float* __restrict__ bnp,
                                                 ushort* __restrict__ zl,
                                                 float* __restrict__ zr) {
  __shared__ float hs[64 * 68];
  __shared__ float ws[32 * 68];
  __shared__ float sc[64], sh[64];
  const int tid = threadIdx.x;
  const int n0 = blockIdx.x * 64;

  if (tid < 64) { sc[tid] = bnp[tid]; sh[tid] = bnp[64 + tid]; }
  for (int i = tid; i < 32 * 16; i += 256) {
    int r = i >> 4, c = i & 15;
    const float* src = (r < 16) ? &W2l[r * 64 + c * 4] : &W2r[(r - 16) * 64 + c * 4];
    *(float4*)&ws[r * 68 + c * 4] = *(const float4*)src;
  }
  __syncthreads();

  for (int i = tid; i < 64 * 16; i += 256) {
    int r = i >> 4, c = i & 15;
    int n = n0 + r;
    float4 v = (n < NN) ? *(const float4*)&hbuf[(size_t)n * 64 + c * 4]
                        : make_float4(0.f, 0.f, 0.f, 0.f);
    float4 o;
    o.x = fmaxf(v.x * sc[c * 4 + 0] + sh[c * 4 + 0], 0.f);
    o.y = fmaxf(v.y * sc[c * 4 + 1] + sh[c * 4 + 1], 0.f);
    o.z = fmaxf(v.z * sc[c * 4 + 2] + sh[c * 4 + 2], 0.f);
    o.w = fmaxf(v.w * sc[c * 4 + 3] + sh[c * 4 + 3], 0.f);
    *(float4*)&hs[r * 68 + c * 4] = o;
  }
  __syncthreads();

  const int og = tid & 7, ng = tid >> 3;
  float acc[4][2] = {};
#pragma unroll
  for (int k4 = 0; k4 < 16; ++k4) {
    float4 wv[4], xv[2];
#pragma unroll
    for (int i = 0; i < 4; ++i) wv[i] = *(float4*)&ws[(og + 8 * i) * 68 + k4 * 4];
#pragma unroll
    for (int j = 0; j < 2; ++j) xv[j] = *(float4*)&hs[(ng + 32 * j) * 68 + k4 * 4];
#pragma unroll
    for (int i = 0; i < 4; ++i)
#pragma unroll
      for (int j = 0; j < 2; ++j)
        acc[i][j] += wv[i].x * xv[j].x + wv[i].y * xv[j].y +
                     wv[i].z * xv[j].z + wv[i].w * xv[j].w;
  }

#pragma unroll
  for (int j = 0; j < 2; ++j) {
    int n = n0 + ng + 32 * j;
    if (n < NN) {
#pragma unroll
      for (int i = 0; i < 4; ++i) {
        int o = og + 8 * i;
        if (o < 16)
          zl[(size_t)n * 16 + o] = f2bf(acc[i][j]);
        else
          zr[(size_t)n * 16 + (o - 16)] = acc[i][j] + b2[o - 16];
      }
    }
  }
}

// ---------------------------------------------------------------------------
// agg2 + out: 8 edges in parallel (sub = lane>>3), lane&7 covers 2 feats (uint)
// ---------------------------------------------------------------------------
__global__ __launch_bounds__(256) void k_agg2(const int* __restrict__ rp,
                                              const int* __restrict__ eidx,
                                              const ushort* __restrict__ zl,
                                              const float* __restrict__ zr,
                                              float* __restrict__ out) {
  int node = blockIdx.x * 4 + (threadIdx.x >> 6);
  int lane = threadIdx.x & 63;
  if (node >= NN) return;
  int f2 = lane & 7, sub = lane >> 3;
  int start = rp[node];
  int end = rp[node + 1];
  float a0 = 0.f, a1 = 0.f;
  for (int k = start + sub; k < end; k += 8) {
    int s = eidx[k];
    unsigned v = *(const unsigned*)&zl[(size_t)s * 16 + f2 * 2];
    a0 += BFLO(v);
    a1 += BFHI(v);
  }
  a0 += __shfl_xor(a0, 8); a0 += __shfl_xor(a0, 16); a0 += __shfl_xor(a0, 32);
  a1 += __shfl_xor(a1, 8); a1 += __shfl_xor(a1, 16); a1 += __shfl_xor(a1, 32);
  if (sub == 0) {
    float invc = 1.0f / fmaxf((float)(end - start), 1.0f);
    size_t base = (size_t)node * 16 + f2 * 2;
    out[base]     = a0 * invc + zr[base];
    out[base + 1] = a1 * invc + zr[base + 1];
  }
}

// ---------------------------------------------------------------------------
extern "C" void kernel_launch(void* const* d_in, const int* in_sizes, int n_in,
                              void* d_out, int out_size, void* d_ws, size_t ws_size,
                              hipStream_t stream) {
  const float* x     = (const float*)d_in[0];
  const int*   ei    = (const int*)d_in[1];
  const float* W1l   = (const float*)d_in[2];
  const float* b1    = (const float*)d_in[3];
  const float* W1r   = (const float*)d_in[4];
  const float* gamma = (const float*)d_in[5];
  const float* beta  = (const float*)d_in[6];
  const float* W2l   = (const float*)d_in[7];
  const float* b2    = (const float*)d_in[8];
  const float* W2r   = (const float*)d_in[9];
  float* out = (float*)d_out;
  float* ws  = (float*)d_ws;

  float*  sums1  = ws + OFF_SUMS1;           // [N,64] f32 -> h in-place
  ushort* yl     = (ushort*)(ws + OFF_YL);   // [N,64] bf16 (12.8MB)
  int2*   ebuf   = (int2*)(ws + OFF_YL);     // overlays (dead before gemm1)
  ushort* zl     = (ushort*)(ws + OFF_YL);   // [N,16] bf16 overlay (yl dead after agg1)
  float*  zr     = ws + OFF_YL + 800000;     // [N,16] f32
  int*    rp     = (int*)(ws + OFF_RP);      // NN+1 start offsets
  int*    eidx   = (int*)(ws + OFF_EIDX);
  int*    bcnt   = (int*)(ws + OFF_BCNT);
  int*    bstart = (int*)(ws + OFF_BSTART);
  int*    bcur   = (int*)(ws + OFF_BCUR);
  int*    bsum   = (int*)(ws + OFF_BSUM);
  float*  bnacc  = ws + OFF_BNACC;
  float*  bnp    = ws + OFF_BNP;
  int*    hist   = (int*)(ws + OFF_SUMS1);   // overlays sums1 (dead after k_bcnt)

  hipMemsetAsync(hist, 0, NN * sizeof(int), stream);
  hipMemsetAsync(bnacc, 0, 128 * sizeof(float), stream);

  const int ntiles = (NN + 63) / 64;         // 1563
  k_hist<<<(NE + 255) / 256, 256, 0, stream>>>(ei, hist);
  k_scan1<<<98, 1024, 0, stream>>>(hist, rp, bsum);
  k_scan2<<<1, 64, 0, stream>>>(bsum);
  k_scan3<<<98, 1024, 0, stream>>>(rp, bsum);
  k_bcnt<<<NB, 256, 0, stream>>>(hist, bcnt);
  k_bscan<<<1, 512, 0, stream>>>(bcnt, bstart, bcur, rp);
  k_part<<<(NE + EPB - 1) / EPB, 256, 0, stream>>>(ei, bcur, ebuf);
  k_fill2<<<NB, 256, 0, stream>>>(rp, bstart, bcur, ebuf, eidx);
  k_gemm1<<<ntiles, 256, 0, stream>>>(x, W1l, yl);
  k_agg1<<<(NN + 3) / 4, 256, 0, stream>>>(rp, eidx, yl, sums1);
  k_l1finish<<<ntiles, 256, 0, stream>>>(x, W1r, b1, rp, sums1, bnacc);
  k_bnfinal<<<1, 64, 0, stream>>>(bnacc, gamma, beta, bnp);
  k_layer2a<<<ntiles, 256, 0, stream>>>(sums1, W2l, W2r, b2, bnp, zl, zr);
  k_agg2<<<(NN + 3) / 4, 256, 0, stream>>>(rp, eidx, zl, zr, out);
}

// Round 8
// 332.618 us; speedup vs baseline: 2.0198x; 1.1073x over previous
//
#include <hip/hip_runtime.h>

#define NN 100000
#define NE 1600000
#define NPB 256                 // nodes per bucket
#define NB 391                  // ceil(NN/NPB)
#define EPB 8192                // edges per partition block

// workspace word offsets
#define OFF_SUMS1  0            // 6,400,000 f  h [N,64] f32; first 100,000 words overlay hist
#define OFF_YL     6400000      // yl bf16 [N,64] (3.2M words); ebuf/zl overlay
#define OFF_YR     9600000      // yr bf16 [N,64] (3.2M words); zr (f32 [N,16]) overlays after agg1f
#define OFF_RP     12800000     // 100,001 i
#define OFF_EIDX   12900032     // 1,600,000 i
#define OFF_BCNT   14500032     // 391 i
#define OFF_BSTART 14500424     // 391 i
#define OFF_BCUR   14500816     // 391 i
#define OFF_BSUM   14501208     // 128 i
#define OFF_BNACC  14501336     // 128 f
#define OFF_BNP    14501464     // 128 f

typedef __attribute__((ext_vector_type(8))) short bf16x8;
typedef __attribute__((ext_vector_type(4))) float f32x4;

__device__ __forceinline__ ushort f2bf(float f) {   // RNE f32 -> bf16
  unsigned u = __float_as_uint(f);
  u += 0x7fffu + ((u >> 16) & 1);
  return (ushort)(u >> 16);
}
#define BFLO(u) __uint_as_float(((u) & 0xffffu) << 16)
#define BFHI(u) __uint_as_float((u) & 0xffff0000u)

// ---------------------------------------------------------------------------
// CSR build (unchanged from round 6)
// ---------------------------------------------------------------------------
__global__ __launch_bounds__(256) void k_hist(const int* __restrict__ ei,
                                              int* __restrict__ hist) {
  int e = blockIdx.x * 256 + threadIdx.x;
  if (e < NE) atomicAdd(&hist[ei[NE + e]], 1);
}

__global__ __launch_bounds__(1024) void k_scan1(const int* __restrict__ hist,
                                                int* __restrict__ rp,
                                                int* __restrict__ bsum) {
  __shared__ int sd[1024];
  int i = blockIdx.x * 1024 + threadIdx.x;
  int v = (i < NN) ? hist[i] : 0;
  sd[threadIdx.x] = v;
  __syncthreads();
  for (int off = 1; off < 1024; off <<= 1) {
    int t = (threadIdx.x >= off) ? sd[threadIdx.x - off] : 0;
    __syncthreads();
    sd[threadIdx.x] += t;
    __syncthreads();
  }
  if (i < NN) rp[i] = sd[threadIdx.x] - v;
  if (threadIdx.x == 1023) bsum[blockIdx.x] = sd[1023];
}

__global__ void k_scan2(int* __restrict__ bsum) {
  if (threadIdx.x == 0) {
    int run = 0;
    for (int b = 0; b < 98; ++b) { int t = bsum[b]; bsum[b] = run; run += t; }
  }
}

__global__ __launch_bounds__(1024) void k_scan3(int* __restrict__ rp,
                                                const int* __restrict__ bsum) {
  int i = blockIdx.x * 1024 + threadIdx.x;
  if (i < NN) rp[i] += bsum[blockIdx.x];
}

__global__ __launch_bounds__(256) void k_bcnt(const int* __restrict__ hist,
                                              int* __restrict__ bcnt) {
  __shared__ int sd[256];
  int node = blockIdx.x * 256 + threadIdx.x;
  sd[threadIdx.x] = (node < NN) ? hist[node] : 0;
  __syncthreads();
  for (int off = 128; off; off >>= 1) {
    if (threadIdx.x < off) sd[threadIdx.x] += sd[threadIdx.x + off];
    __syncthreads();
  }
  if (threadIdx.x == 0) bcnt[blockIdx.x] = sd[0];
}

__global__ __launch_bounds__(512) void k_bscan(const int* __restrict__ bcnt,
                                               int* __restrict__ bstart,
                                               int* __restrict__ bcur,
                                               int* __restrict__ rp) {
  __shared__ int sd[512];
  int v = (threadIdx.x < NB) ? bcnt[threadIdx.x] : 0;
  sd[threadIdx.x] = v;
  __syncthreads();
  for (int off = 1; off < 512; off <<= 1) {
    int t = (threadIdx.x >= off) ? sd[threadIdx.x - off] : 0;
    __syncthreads();
    sd[threadIdx.x] += t;
    __syncthreads();
  }
  if (threadIdx.x < NB) {
    int s = sd[threadIdx.x] - v;
    bstart[threadIdx.x] = s;
    bcur[threadIdx.x] = s;
  }
  if (threadIdx.x == 0) rp[NN] = NE;
}

__global__ __launch_bounds__(256) void k_part(const int* __restrict__ ei,
                                              int* __restrict__ bcur,
                                              int2* __restrict__ ebuf) {
  __shared__ int cnt[NB], gstart[NB], cur[NB];
  int e0 = blockIdx.x * EPB;
  int e1 = min(e0 + EPB, NE);
  for (int i = threadIdx.x; i < NB; i += 256) cnt[i] = 0;
  __syncthreads();
  for (int e = e0 + threadIdx.x; e < e1; e += 256)
    atomicAdd(&cnt[ei[NE + e] >> 8], 1);
  __syncthreads();
  for (int b = threadIdx.x; b < NB; b += 256) {
    int c = cnt[b];
    gstart[b] = c ? atomicAdd(&bcur[b], c) : 0;
    cur[b] = 0;
  }
  __syncthreads();
  for (int e = e0 + threadIdx.x; e < e1; e += 256) {
    int s = ei[e], t = ei[NE + e];
    int b = t >> 8;
    int r = atomicAdd(&cur[b], 1);
    ebuf[gstart[b] + r] = make_int2(s, t);
  }
}

__global__ __launch_bounds__(256) void k_fill2(const int* __restrict__ rp,
                                               const int* __restrict__ bstart,
                                               const int* __restrict__ bcur,
                                               const int2* __restrict__ ebuf,
                                               int* __restrict__ eidx) {
  __shared__ int cur[NPB];
  int b = blockIdx.x;
  int node0 = b << 8;
  int nnode = min(NPB, NN - node0);
  for (int i = threadIdx.x; i < nnode; i += 256) cur[i] = rp[node0 + i];
  __syncthreads();
  int k1 = bcur[b];
  for (int k = bstart[b] + threadIdx.x; k < k1; k += 256) {
    int2 r = ebuf[k];
    int slot = atomicAdd(&cur[r.y - node0], 1);
    eidx[slot] = r.x;
  }
}

// ---------------------------------------------------------------------------
// k_gemm12 (MFMA): yl = x@W1l^T, yr = x@W1r^T  (both bf16 out), x staged once.
// Block = 64 nodes x 128 outs; 4 waves; wave w owns out-tiles 2w, 2w+1.
// mfma_f32_16x16x32_bf16: A lane(l)=x[nt*16+(l&15)][kc*32+(l>>4)*8+j],
// B lane = W[out-tile row (l&15)][same k]; D: col=l&15, row=(l>>4)*4+reg.
// ---------------------------------------------------------------------------
__global__ __launch_bounds__(256) void k_gemm12(const float* __restrict__ x,
                                                const float* __restrict__ W1l,
                                                const float* __restrict__ W1r,
                                                ushort* __restrict__ yl,
                                                ushort* __restrict__ yr) {
  __shared__ ushort xs[64 * 136];    // 17.4 KB, bf16, pad 136 vs 128
  __shared__ ushort wss[128 * 136];  // 34.8 KB (W1l rows 0-63, W1r rows 64-127)
  const int tid = threadIdx.x;
  const int n0 = blockIdx.x * 64;

  for (int i = tid; i < 64 * 32; i += 256) {
    int r = i >> 5, c = i & 31;
    int n = n0 + r;
    float4 v = (n < NN) ? *(const float4*)&x[(size_t)n * 128 + c * 4]
                        : make_float4(0.f, 0.f, 0.f, 0.f);
    ushort4 p = make_ushort4(f2bf(v.x), f2bf(v.y), f2bf(v.z), f2bf(v.w));
    *(ushort4*)&xs[r * 136 + c * 4] = p;
  }
  for (int i = tid; i < 128 * 32; i += 256) {
    int r = i >> 5, c = i & 31;
    const float* src = (r < 64) ? &W1l[r * 128 + c * 4] : &W1r[(r - 64) * 128 + c * 4];
    float4 v = *(const float4*)src;
    ushort4 p = make_ushort4(f2bf(v.x), f2bf(v.y), f2bf(v.z), f2bf(v.w));
    *(ushort4*)&wss[r * 136 + c * 4] = p;
  }
  __syncthreads();

  const int w = tid >> 6, l = tid & 63;
  const int col = l & 15, kb = l >> 4;

  f32x4 acc[4][2];
#pragma unroll
  for (int nt = 0; nt < 4; ++nt)
#pragma unroll
    for (int ot = 0; ot < 2; ++ot) acc[nt][ot] = (f32x4){0.f, 0.f, 0.f, 0.f};

#pragma unroll
  for (int kc = 0; kc < 4; ++kc) {
    int koff = kc * 32 + kb * 8;
    bf16x8 a[4], b[2];
#pragma unroll
    for (int nt = 0; nt < 4; ++nt)
      a[nt] = *(const bf16x8*)&xs[(nt * 16 + col) * 136 + koff];
#pragma unroll
    for (int ot = 0; ot < 2; ++ot)
      b[ot] = *(const bf16x8*)&wss[((w * 2 + ot) * 16 + col) * 136 + koff];
#pragma unroll
    for (int nt = 0; nt < 4; ++nt)
#pragma unroll
      for (int ot = 0; ot < 2; ++ot)
        acc[nt][ot] = __builtin_amdgcn_mfma_f32_16x16x32_bf16(a[nt], b[ot], acc[nt][ot], 0, 0, 0);
  }

#pragma unroll
  for (int nt = 0; nt < 4; ++nt)
#pragma unroll
    for (int ot = 0; ot < 2; ++ot) {
      int outc = (w * 2 + ot) * 16 + col;
#pragma unroll
      for (int r = 0; r < 4; ++r) {
        int n = n0 + nt * 16 + kb * 4 + r;
        if (n < NN) {
          ushort v = f2bf(acc[nt][ot][r]);
          if (outc < 64) yl[(size_t)n * 64 + outc] = v;
          else           yr[(size_t)n * 64 + (outc - 64)] = v;
        }
      }
    }
}

// ---------------------------------------------------------------------------
// k_agg1f: h[n][d] = (sum_{src} yl[src][d]) / deg + b1[d] + yr[n][d]
//          + BN partial sums (register-accumulated, flushed once)
// Wave per node (grid-stride); 4 edges parallel (sub), lane&15 -> 4 feats.
// ---------------------------------------------------------------------------
__global__ __launch_bounds__(256) void k_agg1f(const int* __restrict__ rp,
                                               const int* __restrict__ eidx,
                                               const ushort* __restrict__ yl,
                                               const ushort* __restrict__ yr,
                                               const float* __restrict__ b1,
                                               float* __restrict__ h,
                                               float* __restrict__ bnacc) {
  __shared__ float bnS[64], bnQ[64];
  const int tid = threadIdx.x;
  if (tid < 64) { bnS[tid] = 0.f; bnQ[tid] = 0.f; }
  __syncthreads();
  const int wid = tid >> 6, lane = tid & 63;
  const int f4 = lane & 15, sub = lane >> 4;
  float s0 = 0.f, s1 = 0.f, s2 = 0.f, s3 = 0.f;
  float q0 = 0.f, q1 = 0.f, q2 = 0.f, q3 = 0.f;
  const float4 bv = *(const float4*)&b1[f4 * 4];

  for (int g = blockIdx.x; g < NN / 4; g += 2048) {
    int node = g * 4 + wid;                    // NN % 4 == 0 -> always < NN
    int start = rp[node], end = rp[node + 1];
    float a0 = 0.f, a1 = 0.f, a2 = 0.f, a3 = 0.f;
    for (int k0 = start; k0 < end; k0 += 64) {
      int pre = (k0 + lane < end) ? eidx[k0 + lane] : 0;
      int cnt = min(64, end - k0);
      for (int gg = 0; gg * 4 < cnt; ++gg) {
        int eslot = gg * 4 + sub;
        int s = __shfl(pre, eslot);
        if (eslot < cnt) {
          uint2 v = *(const uint2*)&yl[(size_t)s * 64 + f4 * 4];
          a0 += BFLO(v.x); a1 += BFHI(v.x);
          a2 += BFLO(v.y); a3 += BFHI(v.y);
        }
      }
    }
    a0 += __shfl_xor(a0, 16); a0 += __shfl_xor(a0, 32);
    a1 += __shfl_xor(a1, 16); a1 += __shfl_xor(a1, 32);
    a2 += __shfl_xor(a2, 16); a2 += __shfl_xor(a2, 32);
    a3 += __shfl_xor(a3, 16); a3 += __shfl_xor(a3, 32);
    if (sub == 0) {
      float invc = 1.0f / fmaxf((float)(end - start), 1.0f);
      uint2 rv = *(const uint2*)&yr[(size_t)node * 64 + f4 * 4];
      float h0 = a0 * invc + bv.x + BFLO(rv.x);
      float h1 = a1 * invc + bv.y + BFHI(rv.x);
      float h2 = a2 * invc + bv.z + BFLO(rv.y);
      float h3 = a3 * invc + bv.w + BFHI(rv.y);
      *(float4*)&h[(size_t)node * 64 + f4 * 4] = make_float4(h0, h1, h2, h3);
      s0 += h0; s1 += h1; s2 += h2; s3 += h3;
      q0 += h0 * h0; q1 += h1 * h1; q2 += h2 * h2; q3 += h3 * h3;
    }
  }
  if (sub == 0) {
    atomicAdd(&bnS[f4 * 4 + 0], s0); atomicAdd(&bnQ[f4 * 4 + 0], q0);
    atomicAdd(&bnS[f4 * 4 + 1], s1); atomicAdd(&bnQ[f4 * 4 + 1], q1);
    atomicAdd(&bnS[f4 * 4 + 2], s2); atomicAdd(&bnQ[f4 * 4 + 2], q2);
    atomicAdd(&bnS[f4 * 4 + 3], s3); atomicAdd(&bnQ[f4 * 4 + 3], q3);
  }
  __syncthreads();
  if (tid < 64) {
    atomicAdd(&bnacc[tid], bnS[tid]);
    atomicAdd(&bnacc[64 + tid], bnQ[tid]);
  }
}

// ---------------------------------------------------------------------------
__global__ void k_bnfinal(const float* __restrict__ bnacc,
                          const float* __restrict__ gamma,
                          const float* __restrict__ beta,
                          float* __restrict__ bnp) {
  int o = threadIdx.x;  // 64 threads
  float mean = bnacc[o] * (1.0f / NN);
  float var = bnacc[64 + o] * (1.0f / NN) - mean * mean;
  float sc = gamma[o] * rsqrtf(var + 1e-5f);
  bnp[o] = sc;
  bnp[64 + o] = beta[o] - mean * sc;
}

// ---------------------------------------------------------------------------
// K5: h' = relu(bn(h)); zl = h'@W2_l^T (bf16) ; zr = h'@W2_r^T + b2 (f32)
// ---------------------------------------------------------------------------
__global__ __launch_bounds__(256) void k_layer2a(const float* __restrict__ hbuf,
                                                 const float* __restrict__ W2l,
                                                 const float* __restrict__ W2r,
                                                 const float* __restrict__ b2,
                                                 const float* __restrict__ bnp,
                                                 ushort* __restrict__ zl,
                                                 float* __restrict__ zr) {
  __shared__ float hs[64 * 68];
  __shared__ float ws[32 * 68];
  __shared__ float sc[64], sh[64];
  const int tid = threadIdx.x;
  const int n0 = blockIdx.x * 64;

  if (tid < 64) { sc[tid] = bnp[tid]; sh[tid] = bnp[64 + tid]; }
  for (int i = tid; i < 32 * 16; i += 256) {
    int r = i >> 4, c = i & 15;
    const float* src = (r < 16) ? &W2l[r * 64 + c * 4] : &W2r[(r - 16) * 64 + c * 4];
    *(float4*)&ws[r * 68 + c * 4] = *(const float4*)src;
  }
  __syncthreads();

  for (int i = tid; i < 64 * 16; i += 256) {
    int r = i >> 4, c = i & 15;
    int n = n0 + r;
    float4 v = (n < NN) ? *(const float4*)&hbuf[(size_t)n * 64 + c * 4]
                        : make_float4(0.f, 0.f, 0.f, 0.f);
    float4 o;
    o.x = fmaxf(v.x * sc[c * 4 + 0] + sh[c * 4 + 0], 0.f);
    o.y = fmaxf(v.y * sc[c * 4 + 1] + sh[c * 4 + 1], 0.f);
    o.z = fmaxf(v.z * sc[c * 4 + 2] + sh[c * 4 + 2], 0.f);
    o.w = fmaxf(v.w * sc[c * 4 + 3] + sh[c * 4 + 3], 0.f);
    *(float4*)&hs[r * 68 + c * 4] = o;
  }
  __syncthreads();

  const int og = tid & 7, ng = tid >> 3;
  float acc[4][2] = {};
#pragma unroll
  for (int k4 = 0; k4 < 16; ++k4) {
    float4 wv[4], xv[2];
#pragma unroll
    for (int i = 0; i < 4; ++i) wv[i] = *(float4*)&ws[(og + 8 * i) * 68 + k4 * 4];
#pragma unroll
    for (int j = 0; j < 2; ++j) xv[j] = *(float4*)&hs[(ng + 32 * j) * 68 + k4 * 4];
#pragma unroll
    for (int i = 0; i < 4; ++i)
#pragma unroll
      for (int j = 0; j < 2; ++j)
        acc[i][j] += wv[i].x * xv[j].x + wv[i].y * xv[j].y +
                     wv[i].z * xv[j].z + wv[i].w * xv[j].w;
  }

#pragma unroll
  for (int j = 0; j < 2; ++j) {
    int n = n0 + ng + 32 * j;
    if (n < NN) {
#pragma unroll
      for (int i = 0; i < 4; ++i) {
        int o = og + 8 * i;
        if (o < 16)
          zl[(size_t)n * 16 + o] = f2bf(acc[i][j]);
        else
          zr[(size_t)n * 16 + (o - 16)] = acc[i][j] + b2[o - 16];
      }
    }
  }
}

// ---------------------------------------------------------------------------
// agg2 + out
// ---------------------------------------------------------------------------
__global__ __launch_bounds__(256) void k_agg2(const int* __restrict__ rp,
                                              const int* __restrict__ eidx,
                                              const ushort* __restrict__ zl,
                                              const float* __restrict__ zr,
                                              float* __restrict__ out) {
  int node = blockIdx.x * 4 + (threadIdx.x >> 6);
  int lane = threadIdx.x & 63;
  if (node >= NN) return;
  int f2 = lane & 7, sub = lane >> 3;
  int start = rp[node];
  int end = rp[node + 1];
  float a0 = 0.f, a1 = 0.f;
  for (int k = start + sub; k < end; k += 8) {
    int s = eidx[k];
    unsigned v = *(const unsigned*)&zl[(size_t)s * 16 + f2 * 2];
    a0 += BFLO(v);
    a1 += BFHI(v);
  }
  a0 += __shfl_xor(a0, 8); a0 += __shfl_xor(a0, 16); a0 += __shfl_xor(a0, 32);
  a1 += __shfl_xor(a1, 8); a1 += __shfl_xor(a1, 16); a1 += __shfl_xor(a1, 32);
  if (sub == 0) {
    float invc = 1.0f / fmaxf((float)(end - start), 1.0f);
    size_t base = (size_t)node * 16 + f2 * 2;
    out[base]     = a0 * invc + zr[base];
    out[base + 1] = a1 * invc + zr[base + 1];
  }
}

// ---------------------------------------------------------------------------
extern "C" void kernel_launch(void* const* d_in, const int* in_sizes, int n_in,
                              void* d_out, int out_size, void* d_ws, size_t ws_size,
                              hipStream_t stream) {
  const float* x     = (const float*)d_in[0];
  const int*   ei    = (const int*)d_in[1];
  const float* W1l   = (const float*)d_in[2];
  const float* b1    = (const float*)d_in[3];
  const float* W1r   = (const float*)d_in[4];
  const float* gamma = (const float*)d_in[5];
  const float* beta  = (const float*)d_in[6];
  const float* W2l   = (const float*)d_in[7];
  const float* b2    = (const float*)d_in[8];
  const float* W2r   = (const float*)d_in[9];
  float* out = (float*)d_out;
  float* ws  = (float*)d_ws;

  float*  hbuf   = ws + OFF_SUMS1;           // [N,64] f32 (written by agg1f)
  ushort* yl     = (ushort*)(ws + OFF_YL);   // [N,64] bf16
  ushort* yr     = (ushort*)(ws + OFF_YR);   // [N,64] bf16
  int2*   ebuf   = (int2*)(ws + OFF_YL);     // overlays yl (dead before gemm12)
  ushort* zl     = (ushort*)(ws + OFF_YL);   // [N,16] bf16 (yl dead after agg1f)
  float*  zr     = ws + OFF_YR;              // [N,16] f32 (yr dead after agg1f)
  int*    rp     = (int*)(ws + OFF_RP);
  int*    eidx   = (int*)(ws + OFF_EIDX);
  int*    bcnt   = (int*)(ws + OFF_BCNT);
  int*    bstart = (int*)(ws + OFF_BSTART);
  int*    bcur   = (int*)(ws + OFF_BCUR);
  int*    bsum   = (int*)(ws + OFF_BSUM);
  float*  bnacc  = ws + OFF_BNACC;
  float*  bnp    = ws + OFF_BNP;
  int*    hist   = (int*)(ws + OFF_SUMS1);   // overlays hbuf (dead after k_bcnt)

  hipMemsetAsync(hist, 0, NN * sizeof(int), stream);
  hipMemsetAsync(bnacc, 0, 128 * sizeof(float), stream);

  const int ntiles = (NN + 63) / 64;         // 1563
  k_hist<<<(NE + 255) / 256, 256, 0, stream>>>(ei, hist);
  k_scan1<<<98, 1024, 0, stream>>>(hist, rp, bsum);
  k_scan2<<<1, 64, 0, stream>>>(bsum);
  k_scan3<<<98, 1024, 0, stream>>>(rp, bsum);
  k_bcnt<<<NB, 256, 0, stream>>>(hist, bcnt);
  k_bscan<<<1, 512, 0, stream>>>(bcnt, bstart, bcur, rp);
  k_part<<<(NE + EPB - 1) / EPB, 256, 0, stream>>>(ei, bcur, ebuf);
  k_fill2<<<NB, 256, 0, stream>>>(rp, bstart, bcur, ebuf, eidx);
  k_gemm12<<<ntiles, 256, 0, stream>>>(x, W1l, W1r, yl, yr);
  k_agg1f<<<2048, 256, 0, stream>>>(rp, eidx, yl, yr, b1, hbuf, bnacc);
  k_bnfinal<<<1, 64, 0, stream>>>(bnacc, gamma, beta, bnp);
  k_layer2a<<<ntiles, 256, 0, stream>>>(hbuf, W2l, W2r, b2, bnp, zl, zr);
  k_agg2<<<(NN + 3) / 4, 256, 0, stream>>>(rp, eidx, zl, zr, out);
}

// Round 9
// 324.988 us; speedup vs baseline: 2.0672x; 1.0235x over previous
//
#include <hip/hip_runtime.h>

#define NN 100000
#define NE 1600000
#define NPB 256                 // nodes per bucket
#define NB 391                  // ceil(NN/NPB)
#define EPB 8192                // edges per partition block

// workspace word offsets
#define OFF_SUMS1  0            // 6,400,000 f  h [N,64] f32; first 100,000 words overlay hist
#define OFF_YL     6400000      // yl bf16 [N,64] (3.2M words); ebuf/zl overlay
#define OFF_YR     9600000      // yr bf16 [N,64] (3.2M words); zr (f32 [N,16]) overlays after agg1f
#define OFF_RP     12800000     // 100,001 i
#define OFF_EIDX   12900032     // 1,600,000 i
#define OFF_BCNT   14500032     // 391 i (unused now, kept for layout stability)
#define OFF_BSTART 14500424     // 391 i
#define OFF_BCUR   14500816     // 391 i
#define OFF_BSUM   14501208     // 128 i
#define OFF_BNACC  14501336     // 128 f
#define OFF_BNP    14501464     // 128 f (unused)

typedef __attribute__((ext_vector_type(8))) short bf16x8;
typedef __attribute__((ext_vector_type(4))) float f32x4;

__device__ __forceinline__ ushort f2bf(float f) {   // RNE f32 -> bf16
  unsigned u = __float_as_uint(f);
  u += 0x7fffu + ((u >> 16) & 1);
  return (ushort)(u >> 16);
}
#define BFLO(u) __uint_as_float(((u) & 0xffffu) << 16)
#define BFHI(u) __uint_as_float((u) & 0xffff0000u)

// ---------------------------------------------------------------------------
// degree histogram
// ---------------------------------------------------------------------------
__global__ __launch_bounds__(256) void k_hist(const int* __restrict__ ei,
                                              int* __restrict__ hist) {
  int e = blockIdx.x * 256 + threadIdx.x;
  if (e < NE) atomicAdd(&hist[ei[NE + e]], 1);
}

// exclusive scan over hist -> rp; bsum[b] = block total
__global__ __launch_bounds__(1024) void k_scan1(const int* __restrict__ hist,
                                                int* __restrict__ rp,
                                                int* __restrict__ bsum) {
  __shared__ int sd[1024];
  int i = blockIdx.x * 1024 + threadIdx.x;
  int v = (i < NN) ? hist[i] : 0;
  sd[threadIdx.x] = v;
  __syncthreads();
  for (int off = 1; off < 1024; off <<= 1) {
    int t = (threadIdx.x >= off) ? sd[threadIdx.x - off] : 0;
    __syncthreads();
    sd[threadIdx.x] += t;
    __syncthreads();
  }
  if (i < NN) rp[i] = sd[threadIdx.x] - v;
  if (threadIdx.x == 1023) bsum[blockIdx.x] = sd[1023];
}

// scan3 with absorbed scan2: each block reduces its own exclusive prefix of bsum
__global__ __launch_bounds__(1024) void k_scan3(int* __restrict__ rp,
                                                const int* __restrict__ bsum) {
  __shared__ int pre[128];
  int tid = threadIdx.x;
  if (tid < 128) pre[tid] = (tid < blockIdx.x && tid < 98) ? bsum[tid] : 0;
  __syncthreads();
  for (int off = 64; off; off >>= 1) {
    if (tid < off) pre[tid] += pre[tid + off];
    __syncthreads();
  }
  int i = blockIdx.x * 1024 + tid;
  if (i < NN) rp[i] += pre[0];
}

// bprep = bcnt + bscan merged: per-bucket counts + exclusive scan, one block
__global__ __launch_bounds__(512) void k_bprep(const int* __restrict__ hist,
                                               int* __restrict__ bstart,
                                               int* __restrict__ bcur,
                                               int* __restrict__ rp) {
  __shared__ int sd[512];
  int t = threadIdx.x;
  int acc = 0;
  if (t < NB) {
    int base = t << 8;
    int nnode = min(256, NN - base);
    if (nnode == 256) {
      const int4* hp = (const int4*)(hist + base);
#pragma unroll 4
      for (int i = 0; i < 64; ++i) { int4 v = hp[i]; acc += v.x + v.y + v.z + v.w; }
    } else {
      for (int i = 0; i < nnode; ++i) acc += hist[base + i];
    }
  }
  sd[t] = acc;
  __syncthreads();
  for (int off = 1; off < 512; off <<= 1) {
    int tv = (t >= off) ? sd[t - off] : 0;
    __syncthreads();
    sd[t] += tv;
    __syncthreads();
  }
  if (t < NB) { int s = sd[t] - acc; bstart[t] = s; bcur[t] = s; }
  if (t == 0) rp[NN] = NE;
}

// ---------------------------------------------------------------------------
// partition edges into bucket-contiguous regions of ebuf
// ---------------------------------------------------------------------------
__global__ __launch_bounds__(256) void k_part(const int* __restrict__ ei,
                                              int* __restrict__ bcur,
                                              int2* __restrict__ ebuf) {
  __shared__ int cnt[NB], gstart[NB], cur[NB];
  int e0 = blockIdx.x * EPB;
  int e1 = min(e0 + EPB, NE);
  for (int i = threadIdx.x; i < NB; i += 256) cnt[i] = 0;
  __syncthreads();
  for (int e = e0 + threadIdx.x; e < e1; e += 256)
    atomicAdd(&cnt[ei[NE + e] >> 8], 1);
  __syncthreads();
  for (int b = threadIdx.x; b < NB; b += 256) {
    int c = cnt[b];
    gstart[b] = c ? atomicAdd(&bcur[b], c) : 0;
    cur[b] = 0;
  }
  __syncthreads();
  for (int e = e0 + threadIdx.x; e < e1; e += 256) {
    int s = ei[e], t = ei[NE + e];
    int b = t >> 8;
    int r = atomicAdd(&cur[b], 1);
    ebuf[gstart[b] + r] = make_int2(s, t);
  }
}

__global__ __launch_bounds__(256) void k_fill2(const int* __restrict__ rp,
                                               const int* __restrict__ bstart,
                                               const int* __restrict__ bcur,
                                               const int2* __restrict__ ebuf,
                                               int* __restrict__ eidx) {
  __shared__ int cur[NPB];
  int b = blockIdx.x;
  int node0 = b << 8;
  int nnode = min(NPB, NN - node0);
  for (int i = threadIdx.x; i < nnode; i += 256) cur[i] = rp[node0 + i];
  __syncthreads();
  int k1 = bcur[b];
  for (int k = bstart[b] + threadIdx.x; k < k1; k += 256) {
    int2 r = ebuf[k];
    int slot = atomicAdd(&cur[r.y - node0], 1);
    eidx[slot] = r.x;
  }
}

// ---------------------------------------------------------------------------
// k_gemm12 (MFMA): yl = x@W1l^T, yr = x@W1r^T (both bf16), x staged once.
// ---------------------------------------------------------------------------
__global__ __launch_bounds__(256) void k_gemm12(const float* __restrict__ x,
                                                const float* __restrict__ W1l,
                                                const float* __restrict__ W1r,
                                                ushort* __restrict__ yl,
                                                ushort* __restrict__ yr) {
  __shared__ ushort xs[64 * 136];
  __shared__ ushort wss[128 * 136];
  const int tid = threadIdx.x;
  const int n0 = blockIdx.x * 64;

  for (int i = tid; i < 64 * 32; i += 256) {
    int r = i >> 5, c = i & 31;
    int n = n0 + r;
    float4 v = (n < NN) ? *(const float4*)&x[(size_t)n * 128 + c * 4]
                        : make_float4(0.f, 0.f, 0.f, 0.f);
    *(ushort4*)&xs[r * 136 + c * 4] = make_ushort4(f2bf(v.x), f2bf(v.y), f2bf(v.z), f2bf(v.w));
  }
  for (int i = tid; i < 128 * 32; i += 256) {
    int r = i >> 5, c = i & 31;
    const float* src = (r < 64) ? &W1l[r * 128 + c * 4] : &W1r[(r - 64) * 128 + c * 4];
    float4 v = *(const float4*)src;
    *(ushort4*)&wss[r * 136 + c * 4] = make_ushort4(f2bf(v.x), f2bf(v.y), f2bf(v.z), f2bf(v.w));
  }
  __syncthreads();

  const int w = tid >> 6, l = tid & 63;
  const int col = l & 15, kb = l >> 4;

  f32x4 acc[4][2];
#pragma unroll
  for (int nt = 0; nt < 4; ++nt)
#pragma unroll
    for (int ot = 0; ot < 2; ++ot) acc[nt][ot] = (f32x4){0.f, 0.f, 0.f, 0.f};

#pragma unroll
  for (int kc = 0; kc < 4; ++kc) {
    int koff = kc * 32 + kb * 8;
    bf16x8 a[4], b[2];
#pragma unroll
    for (int nt = 0; nt < 4; ++nt)
      a[nt] = *(const bf16x8*)&xs[(nt * 16 + col) * 136 + koff];
#pragma unroll
    for (int ot = 0; ot < 2; ++ot)
      b[ot] = *(const bf16x8*)&wss[((w * 2 + ot) * 16 + col) * 136 + koff];
#pragma unroll
    for (int nt = 0; nt < 4; ++nt)
#pragma unroll
      for (int ot = 0; ot < 2; ++ot)
        acc[nt][ot] = __builtin_amdgcn_mfma_f32_16x16x32_bf16(a[nt], b[ot], acc[nt][ot], 0, 0, 0);
  }

#pragma unroll
  for (int nt = 0; nt < 4; ++nt)
#pragma unroll
    for (int ot = 0; ot < 2; ++ot) {
      int outc = (w * 2 + ot) * 16 + col;
#pragma unroll
      for (int r = 0; r < 4; ++r) {
        int n = n0 + nt * 16 + kb * 4 + r;
        if (n < NN) {
          ushort v = f2bf(acc[nt][ot][r]);
          if (outc < 64) yl[(size_t)n * 64 + outc] = v;
          else           yr[(size_t)n * 64 + (outc - 64)] = v;
        }
      }
    }
}

// ---------------------------------------------------------------------------
// k_agg1f: h[n][d] = (sum_{src} yl[src][d])/deg + b1[d] + yr[n][d] + BN partials.
// Wave per node; 8 edges parallel (sub=lane>>3), lane&7 -> 8 feats via uint4.
// ---------------------------------------------------------------------------
__global__ __launch_bounds__(256) void k_agg1f(const int* __restrict__ rp,
                                               const int* __restrict__ eidx,
                                               const ushort* __restrict__ yl,
                                               const ushort* __restrict__ yr,
                                               const float* __restrict__ b1,
                                               float* __restrict__ h,
                                               float* __restrict__ bnacc) {
  __shared__ float bnS[64], bnQ[64];
  const int tid = threadIdx.x;
  if (tid < 64) { bnS[tid] = 0.f; bnQ[tid] = 0.f; }
  __syncthreads();
  const int wid = tid >> 6, lane = tid & 63;
  const int f8 = lane & 7, sub = lane >> 3;
  const float4 bv0 = *(const float4*)&b1[f8 * 8];
  const float4 bv1 = *(const float4*)&b1[f8 * 8 + 4];
  float s[8] = {}, q[8] = {};

  for (int g = blockIdx.x; g < NN / 4; g += 2048) {
    int node = g * 4 + wid;
    int start = rp[node], end = rp[node + 1];
    float a[8] = {};
    for (int k0 = start; k0 < end; k0 += 64) {
      int pre = (k0 + lane < end) ? eidx[k0 + lane] : 0;
      int cnt = min(64, end - k0);
      for (int gg = 0; gg * 8 < cnt; ++gg) {
        int eslot = gg * 8 + sub;
        int sr = __shfl(pre, eslot);
        if (eslot < cnt) {
          uint4 v = *(const uint4*)&yl[(size_t)sr * 64 + f8 * 8];
          a[0] += BFLO(v.x); a[1] += BFHI(v.x);
          a[2] += BFLO(v.y); a[3] += BFHI(v.y);
          a[4] += BFLO(v.z); a[5] += BFHI(v.z);
          a[6] += BFLO(v.w); a[7] += BFHI(v.w);
        }
      }
    }
#pragma unroll
    for (int i = 0; i < 8; ++i) {
      a[i] += __shfl_xor(a[i], 8);
      a[i] += __shfl_xor(a[i], 16);
      a[i] += __shfl_xor(a[i], 32);
    }
    if (sub == 0) {
      float invc = 1.0f / fmaxf((float)(end - start), 1.0f);
      uint4 rv = *(const uint4*)&yr[(size_t)node * 64 + f8 * 8];
      float hv[8];
      hv[0] = a[0] * invc + bv0.x + BFLO(rv.x);
      hv[1] = a[1] * invc + bv0.y + BFHI(rv.x);
      hv[2] = a[2] * invc + bv0.z + BFLO(rv.y);
      hv[3] = a[3] * invc + bv0.w + BFHI(rv.y);
      hv[4] = a[4] * invc + bv1.x + BFLO(rv.z);
      hv[5] = a[5] * invc + bv1.y + BFHI(rv.z);
      hv[6] = a[6] * invc + bv1.z + BFLO(rv.w);
      hv[7] = a[7] * invc + bv1.w + BFHI(rv.w);
      *(float4*)&h[(size_t)node * 64 + f8 * 8]     = make_float4(hv[0], hv[1], hv[2], hv[3]);
      *(float4*)&h[(size_t)node * 64 + f8 * 8 + 4] = make_float4(hv[4], hv[5], hv[6], hv[7]);
#pragma unroll
      for (int i = 0; i < 8; ++i) { s[i] += hv[i]; q[i] += hv[i] * hv[i]; }
    }
  }
  if (sub == 0) {
#pragma unroll
    for (int i = 0; i < 8; ++i) {
      atomicAdd(&bnS[f8 * 8 + i], s[i]);
      atomicAdd(&bnQ[f8 * 8 + i], q[i]);
    }
  }
  __syncthreads();
  if (tid < 64) {
    atomicAdd(&bnacc[tid], bnS[tid]);
    atomicAdd(&bnacc[64 + tid], bnQ[tid]);
  }
}

// ---------------------------------------------------------------------------
// k_layer2m (MFMA, BN-finalize fused): h' = relu(bn(h));
// zl = h'@W2_l^T (bf16); zr = h'@W2_r^T + b2 (f32)
// ---------------------------------------------------------------------------
__global__ __launch_bounds__(256) void k_layer2m(const float* __restrict__ h,
                                                 const float* __restrict__ W2l,
                                                 const float* __restrict__ W2r,
                                                 const float* __restrict__ b2,
                                                 const float* __restrict__ bnacc,
                                                 const float* __restrict__ gamma,
                                                 const float* __restrict__ beta,
                                                 ushort* __restrict__ zl,
                                                 float* __restrict__ zr) {
  __shared__ ushort hs[64 * 72];
  __shared__ ushort wss[32 * 72];
  __shared__ float sc[64], sh[64];
  const int tid = threadIdx.x;
  const int n0 = blockIdx.x * 64;

  if (tid < 64) {
    float mean = bnacc[tid] * (1.0f / NN);
    float var = bnacc[64 + tid] * (1.0f / NN) - mean * mean;
    float scv = gamma[tid] * rsqrtf(var + 1e-5f);
    sc[tid] = scv;
    sh[tid] = beta[tid] - mean * scv;
  }
  for (int i = tid; i < 32 * 16; i += 256) {
    int r = i >> 4, c = i & 15;
    const float* src = (r < 16) ? &W2l[r * 64 + c * 4] : &W2r[(r - 16) * 64 + c * 4];
    float4 v = *(const float4*)src;
    *(ushort4*)&wss[r * 72 + c * 4] = make_ushort4(f2bf(v.x), f2bf(v.y), f2bf(v.z), f2bf(v.w));
  }
  __syncthreads();

  for (int i = tid; i < 64 * 16; i += 256) {
    int r = i >> 4, c = i & 15;
    int n = n0 + r;
    float4 v = (n < NN) ? *(const float4*)&h[(size_t)n * 64 + c * 4]
                        : make_float4(0.f, 0.f, 0.f, 0.f);
    float4 o;
    o.x = fmaxf(v.x * sc[c * 4 + 0] + sh[c * 4 + 0], 0.f);
    o.y = fmaxf(v.y * sc[c * 4 + 1] + sh[c * 4 + 1], 0.f);
    o.z = fmaxf(v.z * sc[c * 4 + 2] + sh[c * 4 + 2], 0.f);
    o.w = fmaxf(v.w * sc[c * 4 + 3] + sh[c * 4 + 3], 0.f);
    *(ushort4*)&hs[r * 72 + c * 4] = make_ushort4(f2bf(o.x), f2bf(o.y), f2bf(o.z), f2bf(o.w));
  }
  __syncthreads();

  const int w = tid >> 6, l = tid & 63;
  const int col = l & 15, kb = l >> 4;

  f32x4 acc[2] = {(f32x4){0.f, 0.f, 0.f, 0.f}, (f32x4){0.f, 0.f, 0.f, 0.f}};
#pragma unroll
  for (int kc = 0; kc < 2; ++kc) {
    int koff = kc * 32 + kb * 8;
    bf16x8 a = *(const bf16x8*)&hs[(w * 16 + col) * 72 + koff];
    bf16x8 b0 = *(const bf16x8*)&wss[col * 72 + koff];
    bf16x8 b1v = *(const bf16x8*)&wss[(16 + col) * 72 + koff];
    acc[0] = __builtin_amdgcn_mfma_f32_16x16x32_bf16(a, b0, acc[0], 0, 0, 0);
    acc[1] = __builtin_amdgcn_mfma_f32_16x16x32_bf16(a, b1v, acc[1], 0, 0, 0);
  }

#pragma unroll
  for (int r = 0; r < 4; ++r) {
    int n = n0 + w * 16 + kb * 4 + r;
    if (n < NN) {
      zl[(size_t)n * 16 + col] = f2bf(acc[0][r]);
      zr[(size_t)n * 16 + col] = acc[1][r] + b2[col];
    }
  }
}

// ---------------------------------------------------------------------------
// agg2 + out: 16 edges parallel (sub=lane>>2), lane&3 -> 4 feats via uint2.
// ---------------------------------------------------------------------------
__global__ __launch_bounds__(256) void k_agg2(const int* __restrict__ rp,
                                              const int* __restrict__ eidx,
                                              const ushort* __restrict__ zl,
                                              const float* __restrict__ zr,
                                              float* __restrict__ out) {
  int node = blockIdx.x * 4 + (threadIdx.x >> 6);
  int lane = threadIdx.x & 63;
  if (node >= NN) return;
  int f4 = lane & 3, sub = lane >> 2;
  int start = rp[node];
  int end = rp[node + 1];
  float a0 = 0.f, a1 = 0.f, a2 = 0.f, a3 = 0.f;
  for (int k = start + sub; k < end; k += 16) {
    int s = eidx[k];
    uint2 v = *(const uint2*)&zl[(size_t)s * 16 + f4 * 4];
    a0 += BFLO(v.x); a1 += BFHI(v.x);
    a2 += BFLO(v.y); a3 += BFHI(v.y);
  }
  a0 += __shfl_xor(a0, 4); a0 += __shfl_xor(a0, 8); a0 += __shfl_xor(a0, 16); a0 += __shfl_xor(a0, 32);
  a1 += __shfl_xor(a1, 4); a1 += __shfl_xor(a1, 8); a1 += __shfl_xor(a1, 16); a1 += __shfl_xor(a1, 32);
  a2 += __shfl_xor(a2, 4); a2 += __shfl_xor(a2, 8); a2 += __shfl_xor(a2, 16); a2 += __shfl_xor(a2, 32);
  a3 += __shfl_xor(a3, 4); a3 += __shfl_xor(a3, 8); a3 += __shfl_xor(a3, 16); a3 += __shfl_xor(a3, 32);
  if (sub == 0) {
    float invc = 1.0f / fmaxf((float)(end - start), 1.0f);
    size_t base = (size_t)node * 16 + f4 * 4;
    float4 rv = *(const float4*)&zr[base];
    *(float4*)&out[base] = make_float4(a0 * invc + rv.x, a1 * invc + rv.y,
                                       a2 * invc + rv.z, a3 * invc + rv.w);
  }
}

// ---------------------------------------------------------------------------
extern "C" void kernel_launch(void* const* d_in, const int* in_sizes, int n_in,
                              void* d_out, int out_size, void* d_ws, size_t ws_size,
                              hipStream_t stream) {
  const float* x     = (const float*)d_in[0];
  const int*   ei    = (const int*)d_in[1];
  const float* W1l   = (const float*)d_in[2];
  const float* b1    = (const float*)d_in[3];
  const float* W1r   = (const float*)d_in[4];
  const float* gamma = (const float*)d_in[5];
  const float* beta  = (const float*)d_in[6];
  const float* W2l   = (const float*)d_in[7];
  const float* b2    = (const float*)d_in[8];
  const float* W2r   = (const float*)d_in[9];
  float* out = (float*)d_out;
  float* ws  = (float*)d_ws;

  float*  hbuf   = ws + OFF_SUMS1;
  ushort* yl     = (ushort*)(ws + OFF_YL);
  ushort* yr     = (ushort*)(ws + OFF_YR);
  int2*   ebuf   = (int2*)(ws + OFF_YL);     // overlays yl (dead before gemm12)
  ushort* zl     = (ushort*)(ws + OFF_YL);   // overlays yl (dead after agg1f)
  float*  zr     = ws + OFF_YR;              // overlays yr (dead after agg1f)
  int*    rp     = (int*)(ws + OFF_RP);
  int*    eidx   = (int*)(ws + OFF_EIDX);
  int*    bstart = (int*)(ws + OFF_BSTART);
  int*    bcur   = (int*)(ws + OFF_BCUR);
  int*    bsum   = (int*)(ws + OFF_BSUM);
  float*  bnacc  = ws + OFF_BNACC;
  int*    hist   = (int*)(ws + OFF_SUMS1);   // overlays hbuf (dead after k_bprep)

  hipMemsetAsync(hist, 0, NN * sizeof(int), stream);
  hipMemsetAsync(bnacc, 0, 128 * sizeof(float), stream);

  const int ntiles = (NN + 63) / 64;         // 1563
  k_hist<<<(NE + 255) / 256, 256, 0, stream>>>(ei, hist);
  k_scan1<<<98, 1024, 0, stream>>>(hist, rp, bsum);
  k_scan3<<<98, 1024, 0, stream>>>(rp, bsum);
  k_bprep<<<1, 512, 0, stream>>>(hist, bstart, bcur, rp);
  k_part<<<(NE + EPB - 1) / EPB, 256, 0, stream>>>(ei, bcur, ebuf);
  k_fill2<<<NB, 256, 0, stream>>>(rp, bstart, bcur, ebuf, eidx);
  k_gemm12<<<ntiles, 256, 0, stream>>>(x, W1l, W1r, yl, yr);
  k_agg1f<<<2048, 256, 0, stream>>>(rp, eidx, yl, yr, b1, hbuf, bnacc);
  k_layer2m<<<ntiles, 256, 0, stream>>>(hbuf, W2l, W2r, b2, bnacc, gamma, beta, zl, zr);
  k_agg2<<<(NN + 3) / 4, 256, 0, stream>>>(rp, eidx, zl, zr, out);
}